// Round 2
// baseline (478.759 us; speedup 1.0000x reference)
//
#include <hip/hip_runtime.h>
#include <cfloat>

#define N_NODES 50000
#define N_EDGES 1600000
#define EDGE_TOT (N_EDGES + N_NODES)  // CSR entries incl. self-loops
#define DX      128
#define DH      64
#define KH      4
#define NC      256                   // KH*DH
#define NEG_SLOPE 0.01f
#define SCAN_BLOCKS 196               // bucket count (dst>>8)
#define BIN_BLOCKS 250
#define BIN_CHUNK  6400               // 250*6400 = 1.6M edges exactly

typedef float f2 __attribute__((ext_vector_type(2)));

// ---------- setup: zero bcnt/colsum, transpose Ww (256x128)->Wt(128x256) ----------
__global__ void k_setup(const float* __restrict__ Ww, float* __restrict__ Wt,
                        int* __restrict__ bcnt, float* __restrict__ colsum) {
    int i = blockIdx.x * 256 + threadIdx.x;   // grid 128 -> 32768 threads
    if (i < SCAN_BLOCKS) bcnt[i] = 0;
    if (i < NC) colsum[i] = 0.f;
    {
        int d = i >> 8, c = i & 255;
        Wt[d * NC + c] = Ww[c * DX + d];
    }
}

__device__ __forceinline__ unsigned pack_bf16(float a, float b) {
    unsigned ua = __float_as_uint(a), ub = __float_as_uint(b);
    ua = (ua + 0x7FFFu + ((ua >> 16) & 1u)) >> 16;          // RNE
    ub = (ub + 0x7FFFu + ((ub >> 16) & 1u)) & 0xFFFF0000u;
    return ua | ub;
}

// ---------- Wx GEMM + fused si/sj epilogue; writes bf16 copy for the gather ----------
__global__ void __launch_bounds__(256) k_gemm1(const float* __restrict__ x,
                                               const float* __restrict__ Wt,
                                               const float* __restrict__ Wb,
                                               const float* __restrict__ aw,
                                               const float* __restrict__ ab,
                                               uint2* __restrict__ Wxb,
                                               float* __restrict__ sic,
                                               float* __restrict__ sjc) {
    int wave = blockIdx.x * 4 + __builtin_amdgcn_readfirstlane(threadIdx.x >> 6);
    if (wave >= N_NODES / 8) return;           // 50000 % 8 == 0
    int lane = threadIdx.x & 63;
    int kh = lane >> 4, lq = lane & 15;
    int n0 = wave * 8;
    const float4* WtV = (const float4*)Wt;
    float acc[8][4];
#pragma unroll
    for (int r = 0; r < 8; ++r)
#pragma unroll
        for (int q = 0; q < 4; ++q) acc[r][q] = 0.f;

    for (int d = 0; d < DX; d += 4) {
        float xr[8][4];
#pragma unroll
        for (int r = 0; r < 8; ++r) {
            float4 v = *(const float4*)&x[(size_t)(n0 + r) * DX + d];
            xr[r][0] = v.x; xr[r][1] = v.y; xr[r][2] = v.z; xr[r][3] = v.w;
        }
#pragma unroll
        for (int q = 0; q < 4; ++q) {
            float4 wv = WtV[(size_t)(d + q) * 64 + lane];
#pragma unroll
            for (int r = 0; r < 8; ++r) {
                acc[r][0] += xr[r][q] * wv.x;
                acc[r][1] += xr[r][q] * wv.y;
                acc[r][2] += xr[r][q] * wv.z;
                acc[r][3] += xr[r][q] * wv.w;
            }
        }
    }
    float4 bias = ((const float4*)Wb)[lane];
    const float* awi = aw + kh * 2 * DH + lq * 4;
    const float* awj = awi + DH;
    float ai0 = awi[0], ai1 = awi[1], ai2 = awi[2], ai3 = awi[3];
    float aj0 = awj[0], aj1 = awj[1], aj2 = awj[2], aj3 = awj[3];
    float abk = ab[kh];
#pragma unroll
    for (int r = 0; r < 8; ++r) {
        float o0 = acc[r][0] + bias.x, o1 = acc[r][1] + bias.y;
        float o2 = acc[r][2] + bias.z, o3 = acc[r][3] + bias.w;
        uint2 pk; pk.x = pack_bf16(o0, o1); pk.y = pack_bf16(o2, o3);
        Wxb[(size_t)(n0 + r) * 64 + lane] = pk;
        float pi = o0 * ai0 + o1 * ai1 + o2 * ai2 + o3 * ai3;
        float pj = o0 * aj0 + o1 * aj1 + o2 * aj2 + o3 * aj3;
#pragma unroll
        for (int off = 8; off >= 1; off >>= 1) {
            pi += __shfl_xor(pi, off, 64);
            pj += __shfl_xor(pj, off, 64);
        }
        if (lq == 0) {
            sic[(n0 + r) * 4 + kh] = pi + abk;   // fold ab into dst-side score
            sjc[(n0 + r) * 4 + kh] = pj;
        }
    }
}

// ---------- bucket histogram: 196 bins, LDS-aggregated ----------
__global__ void __launch_bounds__(256) k_bhist(const int* __restrict__ ei,
                                               int* __restrict__ bcnt) {
    __shared__ int bh[SCAN_BLOCKS];
    int t = threadIdx.x;
    if (t < SCAN_BLOCKS) bh[t] = 0;
    __syncthreads();
    int e0 = blockIdx.x * BIN_CHUNK;
#pragma unroll 5
    for (int k = 0; k < BIN_CHUNK / 256; ++k) {
        int dst = ei[N_EDGES + e0 + t + k * 256];
        atomicAdd(&bh[dst >> 8], 1);
    }
    __syncthreads();
    if (t < SCAN_BLOCKS) atomicAdd(&bcnt[t], bh[t]);
}

// ---------- scan 196 bucket counts -> bbase (exclusive) + bcur ----------
__global__ void __launch_bounds__(256) k_scanb(const int* __restrict__ bcnt,
                                               int* __restrict__ bbase,
                                               int* __restrict__ bcur) {
    __shared__ int s[256];
    int t = threadIdx.x;
    int v = (t < SCAN_BLOCKS) ? bcnt[t] : 0;
    s[t] = v;
    __syncthreads();
#pragma unroll
    for (int off = 1; off < 256; off <<= 1) {
        int u = (t >= off) ? s[t - off] : 0;
        __syncthreads();
        s[t] += u;
        __syncthreads();
    }
    if (t < SCAN_BLOCKS) {
        int ex = s[t] - v;
        bbase[t] = ex;
        bcur[t] = ex;
    }
    if (t == SCAN_BLOCKS - 1) bbase[SCAN_BLOCKS] = s[t];   // = N_EDGES
}

// ---------- binning pass: edges -> 196 dst-buckets, dense chunked writes ----------
__global__ void __launch_bounds__(256) k_bin(const int* __restrict__ ei,
                                             int* __restrict__ bcur,
                                             unsigned* __restrict__ binned) {
    __shared__ int bh[SCAN_BLOCKS];   // count, then local cursor
    __shared__ int bb[SCAN_BLOCKS];   // reserved global base
    int t = threadIdx.x;
    if (t < SCAN_BLOCKS) bh[t] = 0;
    __syncthreads();
    int e0 = blockIdx.x * BIN_CHUNK;
#pragma unroll 5
    for (int k = 0; k < BIN_CHUNK / 256; ++k) {
        int dst = ei[N_EDGES + e0 + t + k * 256];
        atomicAdd(&bh[dst >> 8], 1);
    }
    __syncthreads();
    if (t < SCAN_BLOCKS) {
        bb[t] = atomicAdd(&bcur[t], bh[t]);
        bh[t] = 0;
    }
    __syncthreads();
#pragma unroll 5
    for (int k = 0; k < BIN_CHUNK / 256; ++k) {
        int e = e0 + t + k * 256;
        int src = ei[e];
        int dst = ei[N_EDGES + e];
        int b = dst >> 8;
        int lo = atomicAdd(&bh[b], 1);
        binned[bb[b] + lo] = (unsigned)src | ((unsigned)(dst & 255) << 16);   // src < 2^16
    }
}

// ---------- fused per-bucket: count dsts + scan + rowstart + self-loop + scatter ----------
__global__ void __launch_bounds__(256) k_scatter3(const unsigned* __restrict__ binned,
                                                  const int* __restrict__ bbase,
                                                  int* __restrict__ rowstart,
                                                  int* __restrict__ csr_src) {
    __shared__ int lcnt[256];
    __shared__ int lcur[256];
    __shared__ int s[256];
    int t = threadIdx.x, b = blockIdx.x;
    int e0 = bbase[b], e1 = bbase[b + 1];
    lcnt[t] = 0;
    __syncthreads();
    for (int i = e0 + t; i < e1; i += 256)
        atomicAdd(&lcnt[binned[i] >> 16], 1);
    __syncthreads();
    int v = lcnt[t];
    s[t] = v;
    __syncthreads();
#pragma unroll
    for (int off = 1; off < 256; off <<= 1) {
        int u = (t >= off) ? s[t - off] : 0;
        __syncthreads();
        s[t] += u;
        __syncthreads();
    }
    int d = b * 256 + t;
    int base_b = e0 + 256 * b;              // edges before bucket + self-loops before bucket
    if (d < N_NODES) {
        int rs = base_b + (s[t] - v) + t;   // + t self-loops within bucket
        rowstart[d] = rs;
        csr_src[rs] = d;                    // self-loop edge placed first
        lcur[t] = rs + 1;
    } else lcur[t] = 0;
    if (b == 0 && t == 0) rowstart[N_NODES] = N_EDGES + N_NODES;
    __syncthreads();
    for (int i = e0 + t; i < e1; i += 256) {
        unsigned u = binned[i];
        int pos = atomicAdd(&lcur[u >> 16], 1);
        csr_src[pos] = (int)(u & 0xFFFFu);
    }
}

// ---------- edge exp pre-pass: one wave per dst, one lane per edge ----------
// Computes ex for all 4 heads once, streams to exv[head][edge] (SoA) and
// writes 1/den per (dst, head). Removes all per-slice sjc gathers.
__global__ void __launch_bounds__(256) k_edgeexp(const int* __restrict__ rowstart,
                                                 const int* __restrict__ csr_src,
                                                 const float* __restrict__ sic,
                                                 const float* __restrict__ sjc,
                                                 float* __restrict__ exv,
                                                 float* __restrict__ rdn) {
    int dst = blockIdx.x * 4 + (threadIdx.x >> 6);   // grid 12500, exact
    int lane = threadIdx.x & 63;
    int i0 = rowstart[dst], i1 = rowstart[dst + 1];
    float4 si = *(const float4*)&sic[(size_t)dst * 4];   // ab folded into sic
    float den0 = 0.f, den1 = 0.f, den2 = 0.f, den3 = 0.f;
    for (int b = i0; b < i1; b += 64) {
        int idx = b + lane;
        bool act = idx < i1;
        int sl = csr_src[act ? idx : i1 - 1];
        float4 sj = *(const float4*)&sjc[(size_t)sl * 4];
        float e0 = si.x + sj.x, e1 = si.y + sj.y;
        float e2 = si.z + sj.z, e3 = si.w + sj.w;
        e0 = fmaxf(e0, NEG_SLOPE * e0);
        e1 = fmaxf(e1, NEG_SLOPE * e1);
        e2 = fmaxf(e2, NEG_SLOPE * e2);
        e3 = fmaxf(e3, NEG_SLOPE * e3);
        float ex0 = __expf(e0), ex1 = __expf(e1);
        float ex2 = __expf(e2), ex3 = __expf(e3);
        if (act) {
            exv[idx]                = ex0;
            exv[EDGE_TOT + idx]     = ex1;
            exv[2 * EDGE_TOT + idx] = ex2;
            exv[3 * EDGE_TOT + idx] = ex3;
            den0 += ex0; den1 += ex1; den2 += ex2; den3 += ex3;
        }
    }
#pragma unroll
    for (int off = 1; off < 64; off <<= 1) {
        den0 += __shfl_xor(den0, off, 64);
        den1 += __shfl_xor(den1, off, 64);
        den2 += __shfl_xor(den2, off, 64);
        den3 += __shfl_xor(den3, off, 64);
    }
    if (lane == 0) {
        float4 rr;
        rr.x = 1.f / den0; rr.y = 1.f / den1;
        rr.z = 1.f / den2; rr.w = 1.f / den3;
        *(float4*)&rdn[(size_t)dst * 4] = rr;
    }
}

// ---------- sliced aggregation: slice = bid&7 == XCD (round-robin dispatch) ----------
// Each XCD gathers only its 50Kx64B = 3.2MB column slice of Wxb -> L2-resident.
// Wave = one dst x one slice; lane: eg=lane>>3 (edge in group of 8), cp=lane&7
// (uint2 col within slice). One wave-load covers 8 edges' 64B slice rows.
__device__ __forceinline__ void acc_edge(uint2 g, f2 ev, f2& a01, f2& a23) {
    f2 w01, w23;
    w01.x = __uint_as_float(g.x << 16);
    w01.y = __uint_as_float(g.x & 0xFFFF0000u);
    w23.x = __uint_as_float(g.y << 16);
    w23.y = __uint_as_float(g.y & 0xFFFF0000u);
    a01 = __builtin_elementwise_fma(w01, ev, a01);
    a23 = __builtin_elementwise_fma(w23, ev, a23);
}

__global__ void __launch_bounds__(256) k_aggslice(const int* __restrict__ rowstart,
                                                  const int* __restrict__ csr_src,
                                                  const float* __restrict__ exv,
                                                  const float* __restrict__ rdn,
                                                  const uint2* __restrict__ Wxb,
                                                  uint2* __restrict__ expb) {
    int bid = blockIdx.x;
    int slice = bid & 7;                        // pins slice -> XCD
    int wv = __builtin_amdgcn_readfirstlane(threadIdx.x >> 6);
    int dst = (bid >> 3) * 4 + wv;              // grid = 12500*8, exact
    int lane = threadIdx.x & 63;
    int eg = lane >> 3, cp = lane & 7;
    int i0 = rowstart[dst], i1 = rowstart[dst + 1];
    const float* exh = exv + (size_t)(slice >> 1) * EDGE_TOT;
    const char* wxp = (const char*)Wxb + slice * 64 + cp * 8;
    f2 acc01 = {0.f, 0.f}, acc23 = {0.f, 0.f};

    int i = i0;
    for (; i + 32 <= i1; i += 32) {
        int cc[4]; uint2 gg[4]; float ee[4];
#pragma unroll
        for (int u = 0; u < 4; ++u) cc[u] = csr_src[i + u * 8 + eg];
#pragma unroll
        for (int u = 0; u < 4; ++u)
            gg[u] = *(const uint2*)(wxp + ((unsigned)cc[u] << 9));
#pragma unroll
        for (int u = 0; u < 4; ++u) ee[u] = exh[i + u * 8 + eg];
#pragma unroll
        for (int u = 0; u < 4; ++u) {
            f2 ev = {ee[u], ee[u]};
            acc_edge(gg[u], ev, acc01, acc23);
        }
    }
    for (; i < i1; i += 8) {
        int idx = i + eg;
        int c = (idx < i1) ? idx : i1 - 1;
        int s = csr_src[c];
        float ex = (idx < i1) ? exh[c] : 0.f;
        uint2 g = *(const uint2*)(wxp + ((unsigned)s << 9));
        f2 ev = {ex, ex};
        acc_edge(g, ev, acc01, acc23);
    }

#pragma unroll
    for (int off = 8; off <= 32; off <<= 1) {
        acc01.x += __shfl_xor(acc01.x, off, 64);
        acc01.y += __shfl_xor(acc01.y, off, 64);
        acc23.x += __shfl_xor(acc23.x, off, 64);
        acc23.y += __shfl_xor(acc23.y, off, 64);
    }
    if (lane < 8) {
        float r = rdn[(size_t)dst * 4 + (slice >> 1)];
        float o0 = __expf(acc01.x * r), o1 = __expf(acc01.y * r);
        float o2 = __expf(acc23.x * r), o3 = __expf(acc23.y * r);
        uint2 pk; pk.x = pack_bf16(o0, o1); pk.y = pack_bf16(o2, o3);
        expb[(size_t)dst * 64 + slice * 8 + cp] = pk;   // cols 4*(slice*8+cp)..+3
    }
}

// ---------- column sums of exp(agg), bf16 input, 2 cols/thread ----------
__global__ void __launch_bounds__(256) k_colsum(const unsigned* __restrict__ expb,
                                                float* __restrict__ colsum) {
    int tid = threadIdx.x;
    int cp = tid & 127;            // uint index within row (cols 2cp, 2cp+1)
    int ro = tid >> 7;             // row parity
    int base = blockIdx.x * 196;
    int r1 = min(base + 196, N_NODES);
    float s0 = 0.f, s1 = 0.f;
    for (int r = base + ro; r < r1; r += 2) {
        unsigned u = expb[(size_t)r * 128 + cp];
        s0 += __uint_as_float(u << 16);
        s1 += __uint_as_float(u & 0xFFFF0000u);
    }
    atomicAdd(&colsum[2 * cp], s0);
    atomicAdd(&colsum[2 * cp + 1], s1);
}

// ---------- Ws[c][j] = Wo_w[j][c] / colsum[c] ----------
__global__ void k_prepWs(const float* __restrict__ Wo_w, const float* __restrict__ colsum,
                         float* __restrict__ Ws) {
    int i = blockIdx.x * 256 + threadIdx.x;   // 16384 total
    int c = i >> 6, j = i & 63;
    Ws[c * 64 + j] = Wo_w[j * NC + c] / colsum[c];
}

// ---------- out = expb @ Ws + b, LDS-tiled ----------
// j0 MUST be readfirstlane'd: makes Ws reads provably wave-uniform -> s_load.
__global__ void __launch_bounds__(256) k_out(const uint2* __restrict__ expb,
                                             const float* __restrict__ Ws,
                                             const float* __restrict__ Wo_b,
                                             float* __restrict__ out) {
    __shared__ unsigned tile[64][129];
    int n0 = blockIdx.x * 64;
    int rows = min(64, N_NODES - n0);
    int tid = threadIdx.x;

#pragma unroll
    for (int it = 0; it < 16; ++it) {
        int idx = tid + it * 256;          // 64 rows x 64 uint2
        int row = idx >> 6;                // wave-uniform per iteration
        int c4 = idx & 63;                 // lane-contiguous -> 512B bursts
        if (row < rows) {
            uint2 v = expb[(size_t)(n0 + row) * 64 + c4];
            tile[row][c4 * 2] = v.x;
            tile[row][c4 * 2 + 1] = v.y;
        }
    }
    __syncthreads();

    int nl = tid & 63;
    int j0 = __builtin_amdgcn_readfirstlane((tid >> 6) * 16);   // scalarize!
    int nr = min(nl, rows - 1);
    float acc[16];
#pragma unroll
    for (int jj = 0; jj < 16; ++jj) acc[jj] = 0.f;

#pragma unroll 2
    for (int cp = 0; cp < 128; ++cp) {     // 2 cols per iteration
        unsigned u = tile[nr][cp];
        float a0 = __uint_as_float(u << 16);
        float a1 = __uint_as_float(u & 0xFFFF0000u);
        const float* w0 = Ws + (2 * cp) * 64 + j0;   // wave-uniform -> s_load
        const float* w1 = w0 + 64;
#pragma unroll
        for (int jj = 0; jj < 16; ++jj)
            acc[jj] += a0 * w0[jj] + a1 * w1[jj];
    }

    if (nl < rows) {
        float* op = &out[(size_t)(n0 + nl) * DH + j0];
#pragma unroll
        for (int q = 0; q < 4; ++q) {
            float4 o;
            o.x = acc[q * 4 + 0] + Wo_b[j0 + q * 4 + 0];
            o.y = acc[q * 4 + 1] + Wo_b[j0 + q * 4 + 1];
            o.z = acc[q * 4 + 2] + Wo_b[j0 + q * 4 + 2];
            o.w = acc[q * 4 + 3] + Wo_b[j0 + q * 4 + 3];
            *(float4*)(op + q * 4) = o;
        }
    }
}

extern "C" void kernel_launch(void* const* d_in, const int* in_sizes, int n_in,
                              void* d_out, int out_size, void* d_ws, size_t ws_size,
                              hipStream_t stream) {
    const int*   ei   = (const int*)d_in[0];     // int32 from harness
    const float* x    = (const float*)d_in[1];
    const float* Ww   = (const float*)d_in[2];
    const float* Wb   = (const float*)d_in[3];
    const float* aw   = (const float*)d_in[4];
    const float* ab   = (const float*)d_in[5];
    const float* Wo_w = (const float*)d_in[6];
    const float* Wo_b = (const float*)d_in[7];
    float* out = (float*)d_out;

    char* p = (char*)d_ws;
    auto alloc = [&](size_t bytes) -> char* {
        char* q = p;
        p += (bytes + 255) & ~(size_t)255;
        return q;
    };
    uint2*    Wxb      = (uint2*)alloc((size_t)N_NODES * NC * 2);   // bf16 Wx copy
    uint2*    expb     = (uint2*)alloc((size_t)N_NODES * NC * 2);   // bf16 exp(agg)
    float*    Wt       = (float*)alloc((size_t)DX * NC * 4);
    float*    sic      = (float*)alloc((size_t)N_NODES * 4 * 4);
    float*    sjc      = (float*)alloc((size_t)N_NODES * 4 * 4);
    int*      rowstart = (int*)alloc((size_t)(N_NODES + 1) * 4);
    int*      csr_src  = (int*)alloc((size_t)(N_EDGES + N_NODES) * 4);
    float*    exv      = (float*)alloc((size_t)4 * EDGE_TOT * 4);   // SoA [head][edge]
    unsigned* binned   = (unsigned*)exv;        // alias: binned dead before k_edgeexp
    float*    rdn      = (float*)alloc((size_t)N_NODES * 4 * 4);    // 1/den per dst,head
    float*    colsum   = (float*)alloc(NC * 4);
    float*    Ws       = (float*)alloc(NC * DH * 4);
    int*      bcnt     = (int*)alloc(SCAN_BLOCKS * 4);
    int*      bbase    = (int*)alloc((SCAN_BLOCKS + 1) * 4);
    int*      bcur     = (int*)alloc(SCAN_BLOCKS * 4);

    k_setup<<<128, 256, 0, stream>>>(Ww, Wt, bcnt, colsum);
    k_gemm1<<<(N_NODES / 8 + 3) / 4, 256, 0, stream>>>(x, Wt, Wb, aw, ab, Wxb, sic, sjc);
    k_bhist<<<BIN_BLOCKS, 256, 0, stream>>>(ei, bcnt);
    k_scanb<<<1, 256, 0, stream>>>(bcnt, bbase, bcur);
    k_bin<<<BIN_BLOCKS, 256, 0, stream>>>(ei, bcur, binned);
    k_scatter3<<<SCAN_BLOCKS, 256, 0, stream>>>(binned, bbase, rowstart, csr_src);
    k_edgeexp<<<N_NODES / 4, 256, 0, stream>>>(rowstart, csr_src, sic, sjc, exv, rdn);
    k_aggslice<<<(N_NODES / 4) * 8, 256, 0, stream>>>(rowstart, csr_src, exv, rdn, Wxb, expb);
    k_colsum<<<256, 256, 0, stream>>>((const unsigned*)expb, colsum);
    k_prepWs<<<(NC * DH) / 256, 256, 0, stream>>>(Wo_w, colsum, Ws);
    k_out<<<(N_NODES + 63) / 64, 256, 0, stream>>>(expb, Ws, Wo_b, out);
}

// Round 3
// 377.824 us; speedup vs baseline: 1.2671x; 1.2671x over previous
//
#include <hip/hip_runtime.h>
#include <cfloat>

#define N_NODES 50000
#define N_EDGES 1600000
#define DX      128
#define DH      64
#define KH      4
#define NC      256                   // KH*DH
#define NEG_SLOPE 0.01f
#define SCAN_BLOCKS 196               // bucket count (dst>>8)
#define BIN_BLOCKS 250
#define BIN_CHUNK  6400               // 250*6400 = 1.6M edges exactly

typedef float f2 __attribute__((ext_vector_type(2)));
typedef short s8v __attribute__((ext_vector_type(8)));
typedef float f4v __attribute__((ext_vector_type(4)));
typedef unsigned short ushort_t;

__device__ __forceinline__ unsigned pack_bf16(float a, float b) {
    unsigned ua = __float_as_uint(a), ub = __float_as_uint(b);
    ua = (ua + 0x7FFFu + ((ua >> 16) & 1u)) >> 16;          // RNE
    ub = (ub + 0x7FFFu + ((ub >> 16) & 1u)) & 0xFFFF0000u;
    return ua | ub;
}
__device__ __forceinline__ float bflo(unsigned u) { return __uint_as_float(u << 16); }
__device__ __forceinline__ float bfhi(unsigned u) { return __uint_as_float(u & 0xFFFF0000u); }

// ---------- setup: zero bcnt/colsum; build MFMA-lane-ordered bf16 B frags ----------
// Bh/Bl[(kt*16+ct)*64+lane]*8+e  <-  Ww[col][k], col=ct*16+(lane&15),
// k=kt*32+(lane>>4)*8+e.  Bl = bf16 residual (split-GEMM correction term).
__global__ void k_setup(const float* __restrict__ Ww, ushort_t* __restrict__ Bh,
                        ushort_t* __restrict__ Bl,
                        int* __restrict__ bcnt, float* __restrict__ colsum) {
    int i = blockIdx.x * 256 + threadIdx.x;   // grid 128 -> 32768 threads, one bf16 each
    if (i < SCAN_BLOCKS) bcnt[i] = 0;
    if (i < NC) colsum[i] = 0.f;
    int e = i & 7, lane = (i >> 3) & 63, ct = (i >> 9) & 15, kt = (i >> 13) & 3;
    int k = kt * 32 + ((lane >> 4) << 3) + e;
    int c = ct * 16 + (lane & 15);
    float v = Ww[c * DX + k];
    unsigned uv = __float_as_uint(v);
    unsigned vh = (uv + 0x7FFFu + ((uv >> 16) & 1u)) >> 16;
    float rem = v - __uint_as_float(vh << 16);
    unsigned ur = __float_as_uint(rem);
    unsigned vl = (ur + 0x7FFFu + ((ur >> 16) & 1u)) >> 16;
    Bh[i] = (ushort_t)vh;
    Bl[i] = (ushort_t)vl;
}

// ---------- Wx GEMM via MFMA bf16 3-term split + fused si/sj epilogue ----------
// Block = 16 nodes x 256 cols; wave wv owns col-tiles wv*4..wv*4+3.
// A frag: row=lane&15, k=(lane>>4)*8+e (converted from fp32 x in-register).
// D frag: col=lane&15, row=(lane>>4)*4+reg (m89-verified mapping).
__global__ void __launch_bounds__(256) k_gemm1(const float* __restrict__ x,
                                               const uint4* __restrict__ Bh,
                                               const uint4* __restrict__ Bl,
                                               const float* __restrict__ Wb,
                                               const float* __restrict__ aw,
                                               const float* __restrict__ ab,
                                               uint2* __restrict__ Wxb,
                                               float* __restrict__ sic,
                                               float* __restrict__ sjc) {
    __shared__ float lds_wx[16][264];
    int n0b = blockIdx.x * 16;                 // 50000/16 = 3125 exact
    int wv = __builtin_amdgcn_readfirstlane(threadIdx.x >> 6);
    int lane = threadIdx.x & 63;
    int arow = lane & 15, agrp = lane >> 4;
    const float* xr = x + (size_t)(n0b + arow) * DX + agrp * 8;
    f4v acc[4];
#pragma unroll
    for (int ct = 0; ct < 4; ++ct) acc[ct] = {0.f, 0.f, 0.f, 0.f};

#pragma unroll
    for (int kt = 0; kt < 4; ++kt) {
        float4 xa = *(const float4*)(xr + kt * 32);
        float4 xb = *(const float4*)(xr + kt * 32 + 4);
        uint4 h, l;
        h.x = pack_bf16(xa.x, xa.y); h.y = pack_bf16(xa.z, xa.w);
        h.z = pack_bf16(xb.x, xb.y); h.w = pack_bf16(xb.z, xb.w);
        l.x = pack_bf16(xa.x - bflo(h.x), xa.y - bfhi(h.x));
        l.y = pack_bf16(xa.z - bflo(h.y), xa.w - bfhi(h.y));
        l.z = pack_bf16(xb.x - bflo(h.z), xb.y - bfhi(h.z));
        l.w = pack_bf16(xb.z - bflo(h.w), xb.w - bfhi(h.w));
        s8v ah = __builtin_bit_cast(s8v, h);
        s8v al = __builtin_bit_cast(s8v, l);
#pragma unroll
        for (int ct = 0; ct < 4; ++ct) {
            int ctg = wv * 4 + ct;             // global col-tile 0..15
            uint4 bhv = Bh[(kt * 16 + ctg) * 64 + lane];
            uint4 blv = Bl[(kt * 16 + ctg) * 64 + lane];
            s8v bh8 = __builtin_bit_cast(s8v, bhv);
            s8v bl8 = __builtin_bit_cast(s8v, blv);
            acc[ct] = __builtin_amdgcn_mfma_f32_16x16x32_bf16(ah, bh8, acc[ct], 0, 0, 0);
            acc[ct] = __builtin_amdgcn_mfma_f32_16x16x32_bf16(al, bh8, acc[ct], 0, 0, 0);
            acc[ct] = __builtin_amdgcn_mfma_f32_16x16x32_bf16(ah, bl8, acc[ct], 0, 0, 0);
        }
    }
    // scatter D tiles to LDS (col = lane&15, rows = agrp*4+reg)
#pragma unroll
    for (int ct = 0; ct < 4; ++ct) {
        int c = wv * 64 + ct * 16 + arow;
        int r0 = agrp * 4;
        lds_wx[r0 + 0][c] = acc[ct].x;
        lds_wx[r0 + 1][c] = acc[ct].y;
        lds_wx[r0 + 2][c] = acc[ct].z;
        lds_wx[r0 + 3][c] = acc[ct].w;
    }
    __syncthreads();

    // epilogue: wave handles 4 nodes, cols 4*lane..4*lane+3 (same mapping as R1)
    int kh = lane >> 4, lq = lane & 15;
    float4 bias = ((const float4*)Wb)[lane];
    const float* awi = aw + kh * 2 * DH + lq * 4;
    const float* awj = awi + DH;
    float ai0 = awi[0], ai1 = awi[1], ai2 = awi[2], ai3 = awi[3];
    float aj0 = awj[0], aj1 = awj[1], aj2 = awj[2], aj3 = awj[3];
    float abk = ab[kh];
#pragma unroll
    for (int rr = 0; rr < 4; ++rr) {
        int r = wv * 4 + rr;
        float4 o4 = *(float4*)&lds_wx[r][4 * lane];
        float o0 = o4.x + bias.x, o1 = o4.y + bias.y;
        float o2 = o4.z + bias.z, o3 = o4.w + bias.w;
        uint2 pk; pk.x = pack_bf16(o0, o1); pk.y = pack_bf16(o2, o3);
        Wxb[(size_t)(n0b + r) * 64 + lane] = pk;
        float pi = o0 * ai0 + o1 * ai1 + o2 * ai2 + o3 * ai3;
        float pj = o0 * aj0 + o1 * aj1 + o2 * aj2 + o3 * aj3;
#pragma unroll
        for (int off = 8; off >= 1; off >>= 1) {
            pi += __shfl_xor(pi, off, 64);
            pj += __shfl_xor(pj, off, 64);
        }
        if (lq == 0) {
            sic[(n0b + r) * 4 + kh] = pi + abk;   // fold ab into dst-side score
            sjc[(n0b + r) * 4 + kh] = pj;
        }
    }
}

// ---------- bucket histogram: 196 bins, LDS-aggregated ----------
__global__ void __launch_bounds__(256) k_bhist(const int* __restrict__ ei,
                                               int* __restrict__ bcnt) {
    __shared__ int bh[SCAN_BLOCKS];
    int t = threadIdx.x;
    if (t < SCAN_BLOCKS) bh[t] = 0;
    __syncthreads();
    int e0 = blockIdx.x * BIN_CHUNK;
#pragma unroll 5
    for (int k = 0; k < BIN_CHUNK / 256; ++k) {
        int dst = ei[N_EDGES + e0 + t + k * 256];
        atomicAdd(&bh[dst >> 8], 1);
    }
    __syncthreads();
    if (t < SCAN_BLOCKS) atomicAdd(&bcnt[t], bh[t]);
}

// ---------- scan 196 bucket counts -> bbase (exclusive) + bcur ----------
__global__ void __launch_bounds__(256) k_scanb(const int* __restrict__ bcnt,
                                               int* __restrict__ bbase,
                                               int* __restrict__ bcur) {
    __shared__ int s[256];
    int t = threadIdx.x;
    int v = (t < SCAN_BLOCKS) ? bcnt[t] : 0;
    s[t] = v;
    __syncthreads();
#pragma unroll
    for (int off = 1; off < 256; off <<= 1) {
        int u = (t >= off) ? s[t - off] : 0;
        __syncthreads();
        s[t] += u;
        __syncthreads();
    }
    if (t < SCAN_BLOCKS) {
        int ex = s[t] - v;
        bbase[t] = ex;
        bcur[t] = ex;
    }
    if (t == SCAN_BLOCKS - 1) bbase[SCAN_BLOCKS] = s[t];   // = N_EDGES
}

// ---------- binning pass: edges -> 196 dst-buckets, dense chunked writes ----------
__global__ void __launch_bounds__(256) k_bin(const int* __restrict__ ei,
                                             int* __restrict__ bcur,
                                             unsigned* __restrict__ binned) {
    __shared__ int bh[SCAN_BLOCKS];   // count, then local cursor
    __shared__ int bb[SCAN_BLOCKS];   // reserved global base
    int t = threadIdx.x;
    if (t < SCAN_BLOCKS) bh[t] = 0;
    __syncthreads();
    int e0 = blockIdx.x * BIN_CHUNK;
#pragma unroll 5
    for (int k = 0; k < BIN_CHUNK / 256; ++k) {
        int dst = ei[N_EDGES + e0 + t + k * 256];
        atomicAdd(&bh[dst >> 8], 1);
    }
    __syncthreads();
    if (t < SCAN_BLOCKS) {
        bb[t] = atomicAdd(&bcur[t], bh[t]);
        bh[t] = 0;
    }
    __syncthreads();
#pragma unroll 5
    for (int k = 0; k < BIN_CHUNK / 256; ++k) {
        int e = e0 + t + k * 256;
        int src = ei[e];
        int dst = ei[N_EDGES + e];
        int b = dst >> 8;
        int lo = atomicAdd(&bh[b], 1);
        binned[bb[b] + lo] = (unsigned)src | ((unsigned)(dst & 255) << 16);   // src < 2^16
    }
}

// ---------- fused per-bucket: count dsts + scan + rowstart + self-loop + scatter ----------
__global__ void __launch_bounds__(256) k_scatter3(const unsigned* __restrict__ binned,
                                                  const int* __restrict__ bbase,
                                                  int* __restrict__ rowstart,
                                                  int* __restrict__ csr_src) {
    __shared__ int lcnt[256];
    __shared__ int lcur[256];
    __shared__ int s[256];
    int t = threadIdx.x, b = blockIdx.x;
    int e0 = bbase[b], e1 = bbase[b + 1];
    lcnt[t] = 0;
    __syncthreads();
    for (int i = e0 + t; i < e1; i += 256)
        atomicAdd(&lcnt[binned[i] >> 16], 1);
    __syncthreads();
    int v = lcnt[t];
    s[t] = v;
    __syncthreads();
#pragma unroll
    for (int off = 1; off < 256; off <<= 1) {
        int u = (t >= off) ? s[t - off] : 0;
        __syncthreads();
        s[t] += u;
        __syncthreads();
    }
    int d = b * 256 + t;
    int base_b = e0 + 256 * b;              // edges before bucket + self-loops before bucket
    if (d < N_NODES) {
        int rs = base_b + (s[t] - v) + t;   // + t self-loops within bucket
        rowstart[d] = rs;
        csr_src[rs] = d;                    // self-loop edge placed first
        lcur[t] = rs + 1;
    } else lcur[t] = 0;
    if (b == 0 && t == 0) rowstart[N_NODES] = N_EDGES + N_NODES;
    __syncthreads();
    for (int i = e0 + t; i < e1; i += 256) {
        unsigned u = binned[i];
        int pos = atomicAdd(&lcur[u >> 16], 1);
        csr_src[pos] = (int)(u & 0xFFFFu);
    }
}

// ---------- aggregation, two-phase (R1-proven, 114us) ----------
__device__ __forceinline__ void acc_edge(uint2 g, f2 ev, f2& a01, f2& a23) {
    f2 w01, w23;
    w01.x = __uint_as_float(g.x << 16);
    w01.y = __uint_as_float(g.x & 0xFFFF0000u);
    w23.x = __uint_as_float(g.y << 16);
    w23.y = __uint_as_float(g.y & 0xFFFF0000u);
    a01 = __builtin_elementwise_fma(w01, ev, a01);
    a23 = __builtin_elementwise_fma(w23, ev, a23);
}

__global__ void __launch_bounds__(256) k_aggregate(const int* __restrict__ rowstart,
                                                   const int* __restrict__ csr_src,
                                                   const float* __restrict__ sic,
                                                   const float* __restrict__ sjc,
                                                   const uint2* __restrict__ Wxb,
                                                   uint2* __restrict__ expb) {
    __shared__ float exls[4][64 * 8];                 // per-wave: 64 edges x 4 heads, duplicated pairs
    int wv = threadIdx.x >> 6;
    int dst = blockIdx.x * 4 + wv;                    // grid = 12500, exact
    int lane = threadIdx.x & 63;
    int kh = lane >> 4;
    int i0 = rowstart[dst], i1 = rowstart[dst + 1];
    float4 si = *(const float4*)&sic[(size_t)dst * 4];   // broadcast (ab folded into sic)
    float* exl = exls[wv];
    const float* exb = exl + kh * 2;
    const char* wxp = (const char*)Wxb;
    size_t loff = (size_t)lane * 8;

    f2 acc01 = {0.f, 0.f}, acc23 = {0.f, 0.f};
    float den0 = 0.f, den1 = 0.f, den2 = 0.f, den3 = 0.f;

    for (int b = i0; b < i1; b += 64) {
        int cnt = i1 - b;
        if (cnt > 64) cnt = 64;
        // ---- phase A: one edge per lane ----
        int idx = b + lane;
        if (lane >= cnt) idx = i1 - 1;
        int sl = csr_src[idx];
        float ex0 = 0.f, ex1 = 0.f, ex2 = 0.f, ex3 = 0.f;
        if (lane < cnt) {
            float4 sj = *(const float4*)&sjc[(size_t)sl * 4];
            float e0 = si.x + sj.x, e1 = si.y + sj.y;
            float e2 = si.z + sj.z, e3 = si.w + sj.w;
            e0 = fmaxf(e0, NEG_SLOPE * e0);
            e1 = fmaxf(e1, NEG_SLOPE * e1);
            e2 = fmaxf(e2, NEG_SLOPE * e2);
            e3 = fmaxf(e3, NEG_SLOPE * e3);
            ex0 = __expf(e0); ex1 = __expf(e1);
            ex2 = __expf(e2); ex3 = __expf(e3);
            den0 += ex0; den1 += ex1; den2 += ex2; den3 += ex3;
        }
        *(float4*)&exl[lane * 8]     = make_float4(ex0, ex0, ex1, ex1);
        *(float4*)&exl[lane * 8 + 4] = make_float4(ex2, ex2, ex3, ex3);
        asm volatile("" ::: "memory");    // keep phase A stores before phase B reads
        // ---- phase B: lean accumulate over the batch ----
        int e = 0;
        for (; e + 8 <= cnt; e += 8) {
            int ss[8];
#pragma unroll
            for (int u = 0; u < 8; ++u) ss[u] = __builtin_amdgcn_readlane(sl, e + u);
            uint2 gg[8];
#pragma unroll
            for (int u = 0; u < 8; ++u)
                gg[u] = *(const uint2*)(wxp + (((size_t)(unsigned)ss[u]) << 9) + loff);
            f2 ee[8];
#pragma unroll
            for (int u = 0; u < 8; ++u) ee[u] = *(const f2*)&exb[(size_t)(e + u) * 8];
#pragma unroll
            for (int u = 0; u < 8; ++u) acc_edge(gg[u], ee[u], acc01, acc23);
        }
        for (; e < cnt; ++e) {
            int s = __builtin_amdgcn_readlane(sl, e);
            uint2 g = *(const uint2*)(wxp + (((size_t)(unsigned)s) << 9) + loff);
            f2 ev = *(const f2*)&exb[(size_t)e * 8];
            acc_edge(g, ev, acc01, acc23);
        }
        asm volatile("" ::: "memory");    // keep next batch's stores after these reads
    }

    // ---- den reduce: fold the 4 16-lane groups, select my head, butterfly ----
    den0 += __shfl_xor(den0, 16, 64); den0 += __shfl_xor(den0, 32, 64);
    den1 += __shfl_xor(den1, 16, 64); den1 += __shfl_xor(den1, 32, 64);
    den2 += __shfl_xor(den2, 16, 64); den2 += __shfl_xor(den2, 32, 64);
    den3 += __shfl_xor(den3, 16, 64); den3 += __shfl_xor(den3, 32, 64);
    float dsel = (kh < 2) ? ((kh == 0) ? den0 : den1) : ((kh == 2) ? den2 : den3);
    dsel += __shfl_xor(dsel, 1, 64);
    dsel += __shfl_xor(dsel, 2, 64);
    dsel += __shfl_xor(dsel, 4, 64);
    dsel += __shfl_xor(dsel, 8, 64);

    float r = 1.f / dsel;
    float o0 = __expf(acc01.x * r), o1 = __expf(acc01.y * r);
    float o2 = __expf(acc23.x * r), o3 = __expf(acc23.y * r);
    uint2 pk; pk.x = pack_bf16(o0, o1); pk.y = pack_bf16(o2, o3);
    expb[(size_t)dst * 64 + lane] = pk;          // bf16 exp(agg), cols 4l..4l+3
}

// ---------- column sums of exp(agg), bf16 input, 2 cols/thread ----------
__global__ void __launch_bounds__(256) k_colsum(const unsigned* __restrict__ expb,
                                                float* __restrict__ colsum) {
    int tid = threadIdx.x;
    int cp = tid & 127;            // uint index within row (cols 2cp, 2cp+1)
    int ro = tid >> 7;             // row parity
    int base = blockIdx.x * 196;
    int r1 = min(base + 196, N_NODES);
    float s0 = 0.f, s1 = 0.f;
    for (int r = base + ro; r < r1; r += 2) {
        unsigned u = expb[(size_t)r * 128 + cp];
        s0 += __uint_as_float(u << 16);
        s1 += __uint_as_float(u & 0xFFFF0000u);
    }
    atomicAdd(&colsum[2 * cp], s0);
    atomicAdd(&colsum[2 * cp + 1], s1);
}

// ---------- Ws[c][j] = Wo_w[j][c] / colsum[c] ----------
__global__ void k_prepWs(const float* __restrict__ Wo_w, const float* __restrict__ colsum,
                         float* __restrict__ Ws) {
    int i = blockIdx.x * 256 + threadIdx.x;   // 16384 total
    int c = i >> 6, j = i & 63;
    Ws[c * 64 + j] = Wo_w[j * NC + c] / colsum[c];
}

// ---------- out = expb @ Ws + b, LDS-tiled ----------
// j0 MUST be readfirstlane'd: makes Ws reads provably wave-uniform -> s_load.
__global__ void __launch_bounds__(256) k_out(const uint2* __restrict__ expb,
                                             const float* __restrict__ Ws,
                                             const float* __restrict__ Wo_b,
                                             float* __restrict__ out) {
    __shared__ unsigned tile[64][129];
    int n0 = blockIdx.x * 64;
    int rows = min(64, N_NODES - n0);
    int tid = threadIdx.x;

#pragma unroll
    for (int it = 0; it < 16; ++it) {
        int idx = tid + it * 256;          // 64 rows x 64 uint2
        int row = idx >> 6;                // wave-uniform per iteration
        int c4 = idx & 63;                 // lane-contiguous -> 512B bursts
        if (row < rows) {
            uint2 v = expb[(size_t)(n0 + row) * 64 + c4];
            tile[row][c4 * 2] = v.x;
            tile[row][c4 * 2 + 1] = v.y;
        }
    }
    __syncthreads();

    int nl = tid & 63;
    int j0 = __builtin_amdgcn_readfirstlane((tid >> 6) * 16);   // scalarize!
    int nr = min(nl, rows - 1);
    float acc[16];
#pragma unroll
    for (int jj = 0; jj < 16; ++jj) acc[jj] = 0.f;

#pragma unroll 2
    for (int cp = 0; cp < 128; ++cp) {     // 2 cols per iteration
        unsigned u = tile[nr][cp];
        float a0 = __uint_as_float(u << 16);
        float a1 = __uint_as_float(u & 0xFFFF0000u);
        const float* w0 = Ws + (2 * cp) * 64 + j0;   // wave-uniform -> s_load
        const float* w1 = w0 + 64;
#pragma unroll
        for (int jj = 0; jj < 16; ++jj)
            acc[jj] += a0 * w0[jj] + a1 * w1[jj];
    }

    if (nl < rows) {
        float* op = &out[(size_t)(n0 + nl) * DH + j0];
#pragma unroll
        for (int q = 0; q < 4; ++q) {
            float4 o;
            o.x = acc[q * 4 + 0] + Wo_b[j0 + q * 4 + 0];
            o.y = acc[q * 4 + 1] + Wo_b[j0 + q * 4 + 1];
            o.z = acc[q * 4 + 2] + Wo_b[j0 + q * 4 + 2];
            o.w = acc[q * 4 + 3] + Wo_b[j0 + q * 4 + 3];
            *(float4*)(op + q * 4) = o;
        }
    }
}

extern "C" void kernel_launch(void* const* d_in, const int* in_sizes, int n_in,
                              void* d_out, int out_size, void* d_ws, size_t ws_size,
                              hipStream_t stream) {
    const int*   ei   = (const int*)d_in[0];     // int32 from harness
    const float* x    = (const float*)d_in[1];
    const float* Ww   = (const float*)d_in[2];
    const float* Wb   = (const float*)d_in[3];
    const float* aw   = (const float*)d_in[4];
    const float* ab   = (const float*)d_in[5];
    const float* Wo_w = (const float*)d_in[6];
    const float* Wo_b = (const float*)d_in[7];
    float* out = (float*)d_out;

    char* p = (char*)d_ws;
    auto alloc = [&](size_t bytes) -> char* {
        char* q = p;
        p += (bytes + 255) & ~(size_t)255;
        return q;
    };
    uint2*    Wxb      = (uint2*)alloc((size_t)N_NODES * NC * 2);   // bf16 Wx copy
    uint2*    expb     = (uint2*)alloc((size_t)N_NODES * NC * 2);   // bf16 exp(agg)
    ushort_t* Bh       = (ushort_t*)alloc((size_t)DX * NC * 2);     // bf16 W frags (hi)
    ushort_t* Bl       = (ushort_t*)alloc((size_t)DX * NC * 2);     // bf16 W frags (residual)
    float*    sic      = (float*)alloc((size_t)N_NODES * 4 * 4);
    float*    sjc      = (float*)alloc((size_t)N_NODES * 4 * 4);
    int*      rowstart = (int*)alloc((size_t)(N_NODES + 1) * 4);
    int*      csr_src  = (int*)alloc((size_t)(N_EDGES + N_NODES) * 4);
    unsigned* binned   = (unsigned*)alloc((size_t)N_EDGES * 4);
    float*    colsum   = (float*)alloc(NC * 4);
    float*    Ws       = (float*)alloc(NC * DH * 4);
    int*      bcnt     = (int*)alloc(SCAN_BLOCKS * 4);
    int*      bbase    = (int*)alloc((SCAN_BLOCKS + 1) * 4);
    int*      bcur     = (int*)alloc(SCAN_BLOCKS * 4);

    k_setup<<<128, 256, 0, stream>>>(Ww, Bh, Bl, bcnt, colsum);
    k_gemm1<<<N_NODES / 16, 256, 0, stream>>>(x, (const uint4*)Bh, (const uint4*)Bl,
                                              Wb, aw, ab, Wxb, sic, sjc);
    k_bhist<<<BIN_BLOCKS, 256, 0, stream>>>(ei, bcnt);
    k_scanb<<<1, 256, 0, stream>>>(bcnt, bbase, bcur);
    k_bin<<<BIN_BLOCKS, 256, 0, stream>>>(ei, bcur, binned);
    k_scatter3<<<SCAN_BLOCKS, 256, 0, stream>>>(binned, bbase, rowstart, csr_src);
    k_aggregate<<<N_NODES / 4, 256, 0, stream>>>(rowstart, csr_src, sic, sjc, Wxb, expb);
    k_colsum<<<256, 256, 0, stream>>>((const unsigned*)expb, colsum);
    k_prepWs<<<(NC * DH) / 256, 256, 0, stream>>>(Wo_w, colsum, Ws);
    k_out<<<(N_NODES + 63) / 64, 256, 0, stream>>>(expb, Ws, Wo_b, out);
}

// Round 4
// 343.517 us; speedup vs baseline: 1.3937x; 1.0999x over previous
//
#include <hip/hip_runtime.h>
#include <cfloat>

#define N_NODES 50000
#define N_EDGES 1600000
#define DX      128
#define DH      64
#define KH      4
#define NC      256                   // KH*DH
#define NEG_SLOPE 0.01f
#define SCAN_BLOCKS 196               // bucket count (dst>>8)
#define BIN_BLOCKS 250
#define BIN_CHUNK  6400               // 250*6400 = 1.6M edges exactly

typedef float f2 __attribute__((ext_vector_type(2)));
typedef short s8v __attribute__((ext_vector_type(8)));
typedef float f4v __attribute__((ext_vector_type(4)));
typedef unsigned short ushort_t;

__device__ __forceinline__ unsigned pack_bf16(float a, float b) {
    unsigned ua = __float_as_uint(a), ub = __float_as_uint(b);
    ua = (ua + 0x7FFFu + ((ua >> 16) & 1u)) >> 16;          // RNE
    ub = (ub + 0x7FFFu + ((ub >> 16) & 1u)) & 0xFFFF0000u;
    return ua | ub;
}
__device__ __forceinline__ float bflo(unsigned u) { return __uint_as_float(u << 16); }
__device__ __forceinline__ float bfhi(unsigned u) { return __uint_as_float(u & 0xFFFF0000u); }

// ---------- setup: zero bcnt/colsum; build MFMA-lane-ordered bf16 B frags ----------
__global__ void k_setup(const float* __restrict__ Ww, ushort_t* __restrict__ Bh,
                        ushort_t* __restrict__ Bl,
                        int* __restrict__ bcnt, float* __restrict__ colsum) {
    int i = blockIdx.x * 256 + threadIdx.x;   // grid 128 -> 32768 threads, one bf16 each
    if (i < SCAN_BLOCKS) bcnt[i] = 0;
    if (i < NC) colsum[i] = 0.f;
    int e = i & 7, lane = (i >> 3) & 63, ct = (i >> 9) & 15, kt = (i >> 13) & 3;
    int k = kt * 32 + ((lane >> 4) << 3) + e;
    int c = ct * 16 + (lane & 15);
    float v = Ww[c * DX + k];
    unsigned uv = __float_as_uint(v);
    unsigned vh = (uv + 0x7FFFu + ((uv >> 16) & 1u)) >> 16;
    float rem = v - __uint_as_float(vh << 16);
    unsigned ur = __float_as_uint(rem);
    unsigned vl = (ur + 0x7FFFu + ((ur >> 16) & 1u)) >> 16;
    Bh[i] = (ushort_t)vh;
    Bl[i] = (ushort_t)vl;
}

// ---------- Wx GEMM via MFMA bf16 3-term split + int8 quantized epilogue ----------
// Writes Wx8: int8 (biased u8) row of 256 cols per node, scale per (node,head).
// smeta[node] = {sj0..sj3, s0..s3} (32B, gathered once per edge in phase A).
__global__ void __launch_bounds__(256) k_gemm1(const float* __restrict__ x,
                                               const uint4* __restrict__ Bh,
                                               const uint4* __restrict__ Bl,
                                               const float* __restrict__ Wb,
                                               const float* __restrict__ aw,
                                               const float* __restrict__ ab,
                                               unsigned* __restrict__ Wx8,
                                               float* __restrict__ smeta,
                                               float* __restrict__ sic) {
    __shared__ float lds_wx[16][264];
    int n0b = blockIdx.x * 16;                 // 50000/16 = 3125 exact
    int wv = __builtin_amdgcn_readfirstlane(threadIdx.x >> 6);
    int lane = threadIdx.x & 63;
    int arow = lane & 15, agrp = lane >> 4;
    const float* xr = x + (size_t)(n0b + arow) * DX + agrp * 8;
    f4v acc[4];
#pragma unroll
    for (int ct = 0; ct < 4; ++ct) acc[ct] = {0.f, 0.f, 0.f, 0.f};

#pragma unroll
    for (int kt = 0; kt < 4; ++kt) {
        float4 xa = *(const float4*)(xr + kt * 32);
        float4 xb = *(const float4*)(xr + kt * 32 + 4);
        uint4 h, l;
        h.x = pack_bf16(xa.x, xa.y); h.y = pack_bf16(xa.z, xa.w);
        h.z = pack_bf16(xb.x, xb.y); h.w = pack_bf16(xb.z, xb.w);
        l.x = pack_bf16(xa.x - bflo(h.x), xa.y - bfhi(h.x));
        l.y = pack_bf16(xa.z - bflo(h.y), xa.w - bfhi(h.y));
        l.z = pack_bf16(xb.x - bflo(h.z), xb.y - bfhi(h.z));
        l.w = pack_bf16(xb.z - bflo(h.w), xb.w - bfhi(h.w));
        s8v ah = __builtin_bit_cast(s8v, h);
        s8v al = __builtin_bit_cast(s8v, l);
#pragma unroll
        for (int ct = 0; ct < 4; ++ct) {
            int ctg = wv * 4 + ct;             // global col-tile 0..15
            uint4 bhv = Bh[(kt * 16 + ctg) * 64 + lane];
            uint4 blv = Bl[(kt * 16 + ctg) * 64 + lane];
            s8v bh8 = __builtin_bit_cast(s8v, bhv);
            s8v bl8 = __builtin_bit_cast(s8v, blv);
            acc[ct] = __builtin_amdgcn_mfma_f32_16x16x32_bf16(ah, bh8, acc[ct], 0, 0, 0);
            acc[ct] = __builtin_amdgcn_mfma_f32_16x16x32_bf16(al, bh8, acc[ct], 0, 0, 0);
            acc[ct] = __builtin_amdgcn_mfma_f32_16x16x32_bf16(ah, bl8, acc[ct], 0, 0, 0);
        }
    }
    // scatter D tiles to LDS (col = lane&15, rows = agrp*4+reg)
#pragma unroll
    for (int ct = 0; ct < 4; ++ct) {
        int c = wv * 64 + ct * 16 + arow;
        int r0 = agrp * 4;
        lds_wx[r0 + 0][c] = acc[ct].x;
        lds_wx[r0 + 1][c] = acc[ct].y;
        lds_wx[r0 + 2][c] = acc[ct].z;
        lds_wx[r0 + 3][c] = acc[ct].w;
    }
    __syncthreads();

    // epilogue: wave handles 4 nodes, cols 4*lane..4*lane+3
    int kh = lane >> 4, lq = lane & 15;
    float4 bias = ((const float4*)Wb)[lane];
    const float* awi = aw + kh * 2 * DH + lq * 4;
    const float* awj = awi + DH;
    float ai0 = awi[0], ai1 = awi[1], ai2 = awi[2], ai3 = awi[3];
    float aj0 = awj[0], aj1 = awj[1], aj2 = awj[2], aj3 = awj[3];
    float abk = ab[kh];
#pragma unroll
    for (int rr = 0; rr < 4; ++rr) {
        int r = wv * 4 + rr;
        float4 o4 = *(float4*)&lds_wx[r][4 * lane];
        float o0 = o4.x + bias.x, o1 = o4.y + bias.y;
        float o2 = o4.z + bias.z, o3 = o4.w + bias.w;
        float pi = o0 * ai0 + o1 * ai1 + o2 * ai2 + o3 * ai3;
        float pj = o0 * aj0 + o1 * aj1 + o2 * aj2 + o3 * aj3;
        float am = fmaxf(fmaxf(fabsf(o0), fabsf(o1)), fmaxf(fabsf(o2), fabsf(o3)));
#pragma unroll
        for (int off = 8; off >= 1; off >>= 1) {
            pi += __shfl_xor(pi, off, 64);
            pj += __shfl_xor(pj, off, 64);
            am = fmaxf(am, __shfl_xor(am, off, 64));
        }
        am = fmaxf(am, 1e-20f);
        float rs = 127.f / am;
        int q0 = __float2int_rn(o0 * rs) + 128;
        int q1 = __float2int_rn(o1 * rs) + 128;
        int q2 = __float2int_rn(o2 * rs) + 128;
        int q3 = __float2int_rn(o3 * rs) + 128;
        unsigned pk = (unsigned)q0 | ((unsigned)q1 << 8) |
                      ((unsigned)q2 << 16) | ((unsigned)q3 << 24);
        Wx8[(size_t)(n0b + r) * 64 + lane] = pk;
        if (lq == 0) {
            sic[(n0b + r) * 4 + kh] = pi + abk;        // fold ab into dst-side score
            smeta[(size_t)(n0b + r) * 8 + kh] = pj;    // src-side score
            smeta[(size_t)(n0b + r) * 8 + 4 + kh] = am * (1.f / 127.f);  // dequant scale
        }
    }
}

// ---------- bucket histogram: 196 bins, LDS-aggregated ----------
__global__ void __launch_bounds__(256) k_bhist(const int* __restrict__ ei,
                                               int* __restrict__ bcnt) {
    __shared__ int bh[SCAN_BLOCKS];
    int t = threadIdx.x;
    if (t < SCAN_BLOCKS) bh[t] = 0;
    __syncthreads();
    int e0 = blockIdx.x * BIN_CHUNK;
#pragma unroll 5
    for (int k = 0; k < BIN_CHUNK / 256; ++k) {
        int dst = ei[N_EDGES + e0 + t + k * 256];
        atomicAdd(&bh[dst >> 8], 1);
    }
    __syncthreads();
    if (t < SCAN_BLOCKS) atomicAdd(&bcnt[t], bh[t]);
}

// ---------- scan 196 bucket counts -> bbase (exclusive) + bcur ----------
__global__ void __launch_bounds__(256) k_scanb(const int* __restrict__ bcnt,
                                               int* __restrict__ bbase,
                                               int* __restrict__ bcur) {
    __shared__ int s[256];
    int t = threadIdx.x;
    int v = (t < SCAN_BLOCKS) ? bcnt[t] : 0;
    s[t] = v;
    __syncthreads();
#pragma unroll
    for (int off = 1; off < 256; off <<= 1) {
        int u = (t >= off) ? s[t - off] : 0;
        __syncthreads();
        s[t] += u;
        __syncthreads();
    }
    if (t < SCAN_BLOCKS) {
        int ex = s[t] - v;
        bbase[t] = ex;
        bcur[t] = ex;
    }
    if (t == SCAN_BLOCKS - 1) bbase[SCAN_BLOCKS] = s[t];   // = N_EDGES
}

// ---------- binning pass: edges -> 196 dst-buckets, dense chunked writes ----------
__global__ void __launch_bounds__(256) k_bin(const int* __restrict__ ei,
                                             int* __restrict__ bcur,
                                             unsigned* __restrict__ binned) {
    __shared__ int bh[SCAN_BLOCKS];   // count, then local cursor
    __shared__ int bb[SCAN_BLOCKS];   // reserved global base
    int t = threadIdx.x;
    if (t < SCAN_BLOCKS) bh[t] = 0;
    __syncthreads();
    int e0 = blockIdx.x * BIN_CHUNK;
#pragma unroll 5
    for (int k = 0; k < BIN_CHUNK / 256; ++k) {
        int dst = ei[N_EDGES + e0 + t + k * 256];
        atomicAdd(&bh[dst >> 8], 1);
    }
    __syncthreads();
    if (t < SCAN_BLOCKS) {
        bb[t] = atomicAdd(&bcur[t], bh[t]);
        bh[t] = 0;
    }
    __syncthreads();
#pragma unroll 5
    for (int k = 0; k < BIN_CHUNK / 256; ++k) {
        int e = e0 + t + k * 256;
        int src = ei[e];
        int dst = ei[N_EDGES + e];
        int b = dst >> 8;
        int lo = atomicAdd(&bh[b], 1);
        binned[bb[b] + lo] = (unsigned)src | ((unsigned)(dst & 255) << 16);   // src < 2^16
    }
}

// ---------- fused per-bucket: count dsts + scan + rowstart + self-loop + scatter ----------
__global__ void __launch_bounds__(256) k_scatter3(const unsigned* __restrict__ binned,
                                                  const int* __restrict__ bbase,
                                                  int* __restrict__ rowstart,
                                                  int* __restrict__ csr_src) {
    __shared__ int lcnt[256];
    __shared__ int lcur[256];
    __shared__ int s[256];
    int t = threadIdx.x, b = blockIdx.x;
    int e0 = bbase[b], e1 = bbase[b + 1];
    lcnt[t] = 0;
    __syncthreads();
    for (int i = e0 + t; i < e1; i += 256)
        atomicAdd(&lcnt[binned[i] >> 16], 1);
    __syncthreads();
    int v = lcnt[t];
    s[t] = v;
    __syncthreads();
#pragma unroll
    for (int off = 1; off < 256; off <<= 1) {
        int u = (t >= off) ? s[t - off] : 0;
        __syncthreads();
        s[t] += u;
        __syncthreads();
    }
    int d = b * 256 + t;
    int base_b = e0 + 256 * b;              // edges before bucket + self-loops before bucket
    if (d < N_NODES) {
        int rs = base_b + (s[t] - v) + t;   // + t self-loops within bucket
        rowstart[d] = rs;
        csr_src[rs] = d;                    // self-loop edge placed first
        lcur[t] = rs + 1;
    } else lcur[t] = 0;
    if (b == 0 && t == 0) rowstart[N_NODES] = N_EDGES + N_NODES;
    __syncthreads();
    for (int i = e0 + t; i < e1; i += 256) {
        unsigned u = binned[i];
        int pos = atomicAdd(&lcur[u >> 16], 1);
        csr_src[pos] = (int)(u & 0xFFFFu);
    }
}

// ---------- aggregation, two-phase, int8 messages ----------
// phase A (lane==edge): gather smeta (sj+scale, 32B), ex_h = exp(leaky(si+sj)),
//   den += ex, exs = ex*scale, dsum += exs, store exs[4] to wave LDS.
// phase B: readlane(src)->SGPR base; gather 4B of int8 row (wave covers 256B row);
//   acc_c += u8_c * exs (v_cvt_f32_ubyte decode); -128 bias removed via dsum.
__global__ void __launch_bounds__(256) k_aggregate(const int* __restrict__ rowstart,
                                                   const int* __restrict__ csr_src,
                                                   const float* __restrict__ sic,
                                                   const float* __restrict__ smeta,
                                                   const unsigned* __restrict__ Wx8,
                                                   unsigned* __restrict__ expb) {
    __shared__ float exls[4][64 * 4];                 // per-wave: 64 edges x 4 heads
    int wv = threadIdx.x >> 6;
    int dst = blockIdx.x * 4 + wv;                    // grid = 12500, exact
    int lane = threadIdx.x & 63;
    int kh = lane >> 4;
    int i0 = rowstart[dst], i1 = rowstart[dst + 1];
    float4 si = *(const float4*)&sic[(size_t)dst * 4];   // broadcast (ab folded)
    float* exl = exls[wv];
    const float* exb = exl + kh;
    const float4* sm4 = (const float4*)smeta;
    const char* wxp = (const char*)Wx8;
    size_t loff = (size_t)lane * 4;

    float acc0 = 0.f, acc1 = 0.f, acc2 = 0.f, acc3 = 0.f;
    float den0 = 0.f, den1 = 0.f, den2 = 0.f, den3 = 0.f;
    float ds0 = 0.f, ds1 = 0.f, ds2 = 0.f, ds3 = 0.f;

    for (int b = i0; b < i1; b += 64) {
        int cnt = i1 - b;
        if (cnt > 64) cnt = 64;
        // ---- phase A: one edge per lane ----
        int idx = b + lane;
        if (lane >= cnt) idx = i1 - 1;
        int sl = __builtin_nontemporal_load(&csr_src[idx]);
        float4 mj = sm4[(size_t)sl * 2];
        float4 ms = sm4[(size_t)sl * 2 + 1];
        float xs0 = 0.f, xs1 = 0.f, xs2 = 0.f, xs3 = 0.f;
        if (lane < cnt) {
            float e0 = si.x + mj.x, e1 = si.y + mj.y;
            float e2 = si.z + mj.z, e3 = si.w + mj.w;
            e0 = fmaxf(e0, NEG_SLOPE * e0);
            e1 = fmaxf(e1, NEG_SLOPE * e1);
            e2 = fmaxf(e2, NEG_SLOPE * e2);
            e3 = fmaxf(e3, NEG_SLOPE * e3);
            float ex0 = __expf(e0), ex1 = __expf(e1);
            float ex2 = __expf(e2), ex3 = __expf(e3);
            den0 += ex0; den1 += ex1; den2 += ex2; den3 += ex3;
            xs0 = ex0 * ms.x; xs1 = ex1 * ms.y;
            xs2 = ex2 * ms.z; xs3 = ex3 * ms.w;
            ds0 += xs0; ds1 += xs1; ds2 += xs2; ds3 += xs3;
        }
        *(float4*)&exl[lane * 4] = make_float4(xs0, xs1, xs2, xs3);
        asm volatile("" ::: "memory");    // keep phase A stores before phase B reads
        // ---- phase B: lean accumulate over the batch ----
        int e = 0;
        for (; e + 8 <= cnt; e += 8) {
            int ss[8];
#pragma unroll
            for (int u = 0; u < 8; ++u) ss[u] = __builtin_amdgcn_readlane(sl, e + u);
            unsigned gg[8];
#pragma unroll
            for (int u = 0; u < 8; ++u)
                gg[u] = *(const unsigned*)(wxp + (((size_t)(unsigned)ss[u]) << 8) + loff);
            float ee[8];
#pragma unroll
            for (int u = 0; u < 8; ++u) ee[u] = exb[(size_t)(e + u) * 4];
#pragma unroll
            for (int u = 0; u < 8; ++u) {
                acc0 += (float)(gg[u] & 0xFFu) * ee[u];
                acc1 += (float)((gg[u] >> 8) & 0xFFu) * ee[u];
                acc2 += (float)((gg[u] >> 16) & 0xFFu) * ee[u];
                acc3 += (float)(gg[u] >> 24) * ee[u];
            }
        }
        for (; e < cnt; ++e) {
            int s = __builtin_amdgcn_readlane(sl, e);
            unsigned g = *(const unsigned*)(wxp + (((size_t)(unsigned)s) << 8) + loff);
            float ev = exb[(size_t)e * 4];
            acc0 += (float)(g & 0xFFu) * ev;
            acc1 += (float)((g >> 8) & 0xFFu) * ev;
            acc2 += (float)((g >> 16) & 0xFFu) * ev;
            acc3 += (float)(g >> 24) * ev;
        }
        asm volatile("" ::: "memory");    // keep next batch's stores after these reads
    }

    // ---- den/dsum reduce: fold 16-lane groups, select my head, butterfly ----
    den0 += __shfl_xor(den0, 16, 64); den0 += __shfl_xor(den0, 32, 64);
    den1 += __shfl_xor(den1, 16, 64); den1 += __shfl_xor(den1, 32, 64);
    den2 += __shfl_xor(den2, 16, 64); den2 += __shfl_xor(den2, 32, 64);
    den3 += __shfl_xor(den3, 16, 64); den3 += __shfl_xor(den3, 32, 64);
    ds0 += __shfl_xor(ds0, 16, 64); ds0 += __shfl_xor(ds0, 32, 64);
    ds1 += __shfl_xor(ds1, 16, 64); ds1 += __shfl_xor(ds1, 32, 64);
    ds2 += __shfl_xor(ds2, 16, 64); ds2 += __shfl_xor(ds2, 32, 64);
    ds3 += __shfl_xor(ds3, 16, 64); ds3 += __shfl_xor(ds3, 32, 64);
    float dsel  = (kh < 2) ? ((kh == 0) ? den0 : den1) : ((kh == 2) ? den2 : den3);
    float dssel = (kh < 2) ? ((kh == 0) ? ds0  : ds1)  : ((kh == 2) ? ds2  : ds3);
#pragma unroll
    for (int off = 1; off <= 8; off <<= 1) {
        dsel  += __shfl_xor(dsel, off, 64);
        dssel += __shfl_xor(dssel, off, 64);
    }

    float r = 1.f / dsel;
    float bias = 128.f * dssel;
    float o0 = __expf((acc0 - bias) * r), o1 = __expf((acc1 - bias) * r);
    float o2 = __expf((acc2 - bias) * r), o3 = __expf((acc3 - bias) * r);
    unsigned long long pk = (unsigned long long)pack_bf16(o0, o1) |
                            ((unsigned long long)pack_bf16(o2, o3) << 32);
    __builtin_nontemporal_store(pk,
        (unsigned long long*)&expb[(size_t)dst * 128 + lane * 2]);  // bf16, cols 4l..4l+3
}

// ---------- column sums of exp(agg), bf16 input, 2 cols/thread ----------
__global__ void __launch_bounds__(256) k_colsum(const unsigned* __restrict__ expb,
                                                float* __restrict__ colsum) {
    int tid = threadIdx.x;
    int cp = tid & 127;            // uint index within row (cols 2cp, 2cp+1)
    int ro = tid >> 7;             // row parity
    int base = blockIdx.x * 196;
    int r1 = min(base + 196, N_NODES);
    float s0 = 0.f, s1 = 0.f;
    for (int r = base + ro; r < r1; r += 2) {
        unsigned u = expb[(size_t)r * 128 + cp];
        s0 += __uint_as_float(u << 16);
        s1 += __uint_as_float(u & 0xFFFF0000u);
    }
    atomicAdd(&colsum[2 * cp], s0);
    atomicAdd(&colsum[2 * cp + 1], s1);
}

// ---------- Ws[c][j] = Wo_w[j][c] / colsum[c] ----------
__global__ void k_prepWs(const float* __restrict__ Wo_w, const float* __restrict__ colsum,
                         float* __restrict__ Ws) {
    int i = blockIdx.x * 256 + threadIdx.x;   // 16384 total
    int c = i >> 6, j = i & 63;
    Ws[c * 64 + j] = Wo_w[j * NC + c] / colsum[c];
}

// ---------- out = expb @ Ws + b, LDS-tiled ----------
__global__ void __launch_bounds__(256) k_out(const uint2* __restrict__ expb,
                                             const float* __restrict__ Ws,
                                             const float* __restrict__ Wo_b,
                                             float* __restrict__ out) {
    __shared__ unsigned tile[64][129];
    int n0 = blockIdx.x * 64;
    int rows = min(64, N_NODES - n0);
    int tid = threadIdx.x;

#pragma unroll
    for (int it = 0; it < 16; ++it) {
        int idx = tid + it * 256;          // 64 rows x 64 uint2
        int row = idx >> 6;                // wave-uniform per iteration
        int c4 = idx & 63;                 // lane-contiguous -> 512B bursts
        if (row < rows) {
            uint2 v = expb[(size_t)(n0 + row) * 64 + c4];
            tile[row][c4 * 2] = v.x;
            tile[row][c4 * 2 + 1] = v.y;
        }
    }
    __syncthreads();

    int nl = tid & 63;
    int j0 = __builtin_amdgcn_readfirstlane((tid >> 6) * 16);   // scalarize!
    int nr = min(nl, rows - 1);
    float acc[16];
#pragma unroll
    for (int jj = 0; jj < 16; ++jj) acc[jj] = 0.f;

#pragma unroll 2
    for (int cp = 0; cp < 128; ++cp) {     // 2 cols per iteration
        unsigned u = tile[nr][cp];
        float a0 = __uint_as_float(u << 16);
        float a1 = __uint_as_float(u & 0xFFFF0000u);
        const float* w0 = Ws + (2 * cp) * 64 + j0;   // wave-uniform -> s_load
        const float* w1 = w0 + 64;
#pragma unroll
        for (int jj = 0; jj < 16; ++jj)
            acc[jj] += a0 * w0[jj] + a1 * w1[jj];
    }

    if (nl < rows) {
        float* op = &out[(size_t)(n0 + nl) * DH + j0];
#pragma unroll
        for (int q = 0; q < 4; ++q) {
            float4 o;
            o.x = acc[q * 4 + 0] + Wo_b[j0 + q * 4 + 0];
            o.y = acc[q * 4 + 1] + Wo_b[j0 + q * 4 + 1];
            o.z = acc[q * 4 + 2] + Wo_b[j0 + q * 4 + 2];
            o.w = acc[q * 4 + 3] + Wo_b[j0 + q * 4 + 3];
            *(float4*)(op + q * 4) = o;
        }
    }
}

extern "C" void kernel_launch(void* const* d_in, const int* in_sizes, int n_in,
                              void* d_out, int out_size, void* d_ws, size_t ws_size,
                              hipStream_t stream) {
    const int*   ei   = (const int*)d_in[0];     // int32 from harness
    const float* x    = (const float*)d_in[1];
    const float* Ww   = (const float*)d_in[2];
    const float* Wb   = (const float*)d_in[3];
    const float* aw   = (const float*)d_in[4];
    const float* ab   = (const float*)d_in[5];
    const float* Wo_w = (const float*)d_in[6];
    const float* Wo_b = (const float*)d_in[7];
    float* out = (float*)d_out;

    char* p = (char*)d_ws;
    auto alloc = [&](size_t bytes) -> char* {
        char* q = p;
        p += (bytes + 255) & ~(size_t)255;
        return q;
    };
    unsigned* Wx8      = (unsigned*)alloc((size_t)N_NODES * NC);    // int8 Wx copy (12.8MB)
    unsigned* expb     = (unsigned*)alloc((size_t)N_NODES * NC * 2);// bf16 exp(agg)
    ushort_t* Bh       = (ushort_t*)alloc((size_t)DX * NC * 2);     // bf16 W frags (hi)
    ushort_t* Bl       = (ushort_t*)alloc((size_t)DX * NC * 2);     // bf16 W frags (residual)
    float*    smeta    = (float*)alloc((size_t)N_NODES * 8 * 4);    // {sj[4], scale[4]} per node
    float*    sic      = (float*)alloc((size_t)N_NODES * 4 * 4);
    int*      rowstart = (int*)alloc((size_t)(N_NODES + 1) * 4);
    int*      csr_src  = (int*)alloc((size_t)(N_EDGES + N_NODES) * 4);
    unsigned* binned   = (unsigned*)alloc((size_t)N_EDGES * 4);
    float*    colsum   = (float*)alloc(NC * 4);
    float*    Ws       = (float*)alloc(NC * DH * 4);
    int*      bcnt     = (int*)alloc(SCAN_BLOCKS * 4);
    int*      bbase    = (int*)alloc((SCAN_BLOCKS + 1) * 4);
    int*      bcur     = (int*)alloc(SCAN_BLOCKS * 4);

    k_setup<<<128, 256, 0, stream>>>(Ww, Bh, Bl, bcnt, colsum);
    k_gemm1<<<N_NODES / 16, 256, 0, stream>>>(x, (const uint4*)Bh, (const uint4*)Bl,
                                              Wb, aw, ab, Wx8, smeta, sic);
    k_bhist<<<BIN_BLOCKS, 256, 0, stream>>>(ei, bcnt);
    k_scanb<<<1, 256, 0, stream>>>(bcnt, bbase, bcur);
    k_bin<<<BIN_BLOCKS, 256, 0, stream>>>(ei, bcur, binned);
    k_scatter3<<<SCAN_BLOCKS, 256, 0, stream>>>(binned, bbase, rowstart, csr_src);
    k_aggregate<<<N_NODES / 4, 256, 0, stream>>>(rowstart, csr_src, sic, smeta, Wx8, expb);
    k_colsum<<<256, 256, 0, stream>>>(expb, colsum);
    k_prepWs<<<(NC * DH) / 256, 256, 0, stream>>>(Wo_w, colsum, Ws);
    k_out<<<(N_NODES + 63) / 64, 256, 0, stream>>>((const uint2*)expb, Ws, Wo_b, out);
}

// Round 5
// 319.515 us; speedup vs baseline: 1.4984x; 1.0751x over previous
//
#include <hip/hip_runtime.h>
#include <cfloat>

#define N_NODES 50000
#define N_EDGES 1600000
#define DX      128
#define DH      64
#define KH      4
#define NC      256                   // KH*DH
#define NEG_SLOPE 0.01f
#define SCAN_BLOCKS 196               // bucket count (dst>>8)
#define BIN_BLOCKS 250
#define BIN_CHUNK  6400               // 250*6400 = 1.6M edges exactly

typedef float f2 __attribute__((ext_vector_type(2)));
typedef short s8v __attribute__((ext_vector_type(8)));
typedef float f4v __attribute__((ext_vector_type(4)));
typedef unsigned short ushort_t;

__device__ __forceinline__ unsigned pack_bf16(float a, float b) {
    unsigned ua = __float_as_uint(a), ub = __float_as_uint(b);
    ua = (ua + 0x7FFFu + ((ua >> 16) & 1u)) >> 16;          // RNE
    ub = (ub + 0x7FFFu + ((ub >> 16) & 1u)) & 0xFFFF0000u;
    return ua | ub;
}
__device__ __forceinline__ float bflo(unsigned u) { return __uint_as_float(u << 16); }
__device__ __forceinline__ float bfhi(unsigned u) { return __uint_as_float(u & 0xFFFF0000u); }

// ---------- setup: zero bcnt/colsum; build MFMA-lane-ordered bf16 B frags ----------
__global__ void k_setup(const float* __restrict__ Ww, ushort_t* __restrict__ Bh,
                        ushort_t* __restrict__ Bl,
                        int* __restrict__ bcnt, float* __restrict__ colsum) {
    int i = blockIdx.x * 256 + threadIdx.x;   // grid 128 -> 32768 threads, one bf16 each
    if (i < SCAN_BLOCKS) bcnt[i] = 0;
    if (i < NC) colsum[i] = 0.f;
    int e = i & 7, lane = (i >> 3) & 63, ct = (i >> 9) & 15, kt = (i >> 13) & 3;
    int k = kt * 32 + ((lane >> 4) << 3) + e;
    int c = ct * 16 + (lane & 15);
    float v = Ww[c * DX + k];
    unsigned uv = __float_as_uint(v);
    unsigned vh = (uv + 0x7FFFu + ((uv >> 16) & 1u)) >> 16;
    float rem = v - __uint_as_float(vh << 16);
    unsigned ur = __float_as_uint(rem);
    unsigned vl = (ur + 0x7FFFu + ((ur >> 16) & 1u)) >> 16;
    Bh[i] = (ushort_t)vh;
    Bl[i] = (ushort_t)vl;
}

// ---------- Wx GEMM via MFMA bf16 3-term split + int8 quantized epilogue ----------
__global__ void __launch_bounds__(256) k_gemm1(const float* __restrict__ x,
                                               const uint4* __restrict__ Bh,
                                               const uint4* __restrict__ Bl,
                                               const float* __restrict__ Wb,
                                               const float* __restrict__ aw,
                                               const float* __restrict__ ab,
                                               unsigned* __restrict__ Wx8,
                                               float* __restrict__ smeta,
                                               float* __restrict__ sic) {
    __shared__ float lds_wx[16][264];
    int n0b = blockIdx.x * 16;                 // 50000/16 = 3125 exact
    int wv = __builtin_amdgcn_readfirstlane(threadIdx.x >> 6);
    int lane = threadIdx.x & 63;
    int arow = lane & 15, agrp = lane >> 4;
    const float* xr = x + (size_t)(n0b + arow) * DX + agrp * 8;
    f4v acc[4];
#pragma unroll
    for (int ct = 0; ct < 4; ++ct) acc[ct] = {0.f, 0.f, 0.f, 0.f};

#pragma unroll
    for (int kt = 0; kt < 4; ++kt) {
        float4 xa = *(const float4*)(xr + kt * 32);
        float4 xb = *(const float4*)(xr + kt * 32 + 4);
        uint4 h, l;
        h.x = pack_bf16(xa.x, xa.y); h.y = pack_bf16(xa.z, xa.w);
        h.z = pack_bf16(xb.x, xb.y); h.w = pack_bf16(xb.z, xb.w);
        l.x = pack_bf16(xa.x - bflo(h.x), xa.y - bfhi(h.x));
        l.y = pack_bf16(xa.z - bflo(h.y), xa.w - bfhi(h.y));
        l.z = pack_bf16(xb.x - bflo(h.z), xb.y - bfhi(h.z));
        l.w = pack_bf16(xb.z - bflo(h.w), xb.w - bfhi(h.w));
        s8v ah = __builtin_bit_cast(s8v, h);
        s8v al = __builtin_bit_cast(s8v, l);
#pragma unroll
        for (int ct = 0; ct < 4; ++ct) {
            int ctg = wv * 4 + ct;             // global col-tile 0..15
            uint4 bhv = Bh[(kt * 16 + ctg) * 64 + lane];
            uint4 blv = Bl[(kt * 16 + ctg) * 64 + lane];
            s8v bh8 = __builtin_bit_cast(s8v, bhv);
            s8v bl8 = __builtin_bit_cast(s8v, blv);
            acc[ct] = __builtin_amdgcn_mfma_f32_16x16x32_bf16(ah, bh8, acc[ct], 0, 0, 0);
            acc[ct] = __builtin_amdgcn_mfma_f32_16x16x32_bf16(al, bh8, acc[ct], 0, 0, 0);
            acc[ct] = __builtin_amdgcn_mfma_f32_16x16x32_bf16(ah, bl8, acc[ct], 0, 0, 0);
        }
    }
    // scatter D tiles to LDS (col = lane&15, rows = agrp*4+reg)
#pragma unroll
    for (int ct = 0; ct < 4; ++ct) {
        int c = wv * 64 + ct * 16 + arow;
        int r0 = agrp * 4;
        lds_wx[r0 + 0][c] = acc[ct].x;
        lds_wx[r0 + 1][c] = acc[ct].y;
        lds_wx[r0 + 2][c] = acc[ct].z;
        lds_wx[r0 + 3][c] = acc[ct].w;
    }
    __syncthreads();

    // epilogue: wave handles 4 nodes, cols 4*lane..4*lane+3
    int kh = lane >> 4, lq = lane & 15;
    float4 bias = ((const float4*)Wb)[lane];
    const float* awi = aw + kh * 2 * DH + lq * 4;
    const float* awj = awi + DH;
    float ai0 = awi[0], ai1 = awi[1], ai2 = awi[2], ai3 = awi[3];
    float aj0 = awj[0], aj1 = awj[1], aj2 = awj[2], aj3 = awj[3];
    float abk = ab[kh];
#pragma unroll
    for (int rr = 0; rr < 4; ++rr) {
        int r = wv * 4 + rr;
        float4 o4 = *(float4*)&lds_wx[r][4 * lane];
        float o0 = o4.x + bias.x, o1 = o4.y + bias.y;
        float o2 = o4.z + bias.z, o3 = o4.w + bias.w;
        float pi = o0 * ai0 + o1 * ai1 + o2 * ai2 + o3 * ai3;
        float pj = o0 * aj0 + o1 * aj1 + o2 * aj2 + o3 * aj3;
        float am = fmaxf(fmaxf(fabsf(o0), fabsf(o1)), fmaxf(fabsf(o2), fabsf(o3)));
#pragma unroll
        for (int off = 8; off >= 1; off >>= 1) {
            pi += __shfl_xor(pi, off, 64);
            pj += __shfl_xor(pj, off, 64);
            am = fmaxf(am, __shfl_xor(am, off, 64));
        }
        am = fmaxf(am, 1e-20f);
        float rs = 127.f / am;
        int q0 = __float2int_rn(o0 * rs) + 128;
        int q1 = __float2int_rn(o1 * rs) + 128;
        int q2 = __float2int_rn(o2 * rs) + 128;
        int q3 = __float2int_rn(o3 * rs) + 128;
        unsigned pk = (unsigned)q0 | ((unsigned)q1 << 8) |
                      ((unsigned)q2 << 16) | ((unsigned)q3 << 24);
        Wx8[(size_t)(n0b + r) * 64 + lane] = pk;
        if (lq == 0) {
            sic[(n0b + r) * 4 + kh] = pi + abk;        // fold ab into dst-side score
            smeta[(size_t)(n0b + r) * 8 + kh] = pj;    // src-side score
            smeta[(size_t)(n0b + r) * 8 + 4 + kh] = am * (1.f / 127.f);  // dequant scale
        }
    }
}

// ---------- bucket histogram: 196 bins, LDS-aggregated ----------
__global__ void __launch_bounds__(256) k_bhist(const int* __restrict__ ei,
                                               int* __restrict__ bcnt) {
    __shared__ int bh[SCAN_BLOCKS];
    int t = threadIdx.x;
    if (t < SCAN_BLOCKS) bh[t] = 0;
    __syncthreads();
    int e0 = blockIdx.x * BIN_CHUNK;
#pragma unroll 5
    for (int k = 0; k < BIN_CHUNK / 256; ++k) {
        int dst = ei[N_EDGES + e0 + t + k * 256];
        atomicAdd(&bh[dst >> 8], 1);
    }
    __syncthreads();
    if (t < SCAN_BLOCKS) atomicAdd(&bcnt[t], bh[t]);
}

// ---------- scan 196 bucket counts -> bbase (exclusive) + bcur ----------
__global__ void __launch_bounds__(256) k_scanb(const int* __restrict__ bcnt,
                                               int* __restrict__ bbase,
                                               int* __restrict__ bcur) {
    __shared__ int s[256];
    int t = threadIdx.x;
    int v = (t < SCAN_BLOCKS) ? bcnt[t] : 0;
    s[t] = v;
    __syncthreads();
#pragma unroll
    for (int off = 1; off < 256; off <<= 1) {
        int u = (t >= off) ? s[t - off] : 0;
        __syncthreads();
        s[t] += u;
        __syncthreads();
    }
    if (t < SCAN_BLOCKS) {
        int ex = s[t] - v;
        bbase[t] = ex;
        bcur[t] = ex;
    }
    if (t == SCAN_BLOCKS - 1) bbase[SCAN_BLOCKS] = s[t];   // = N_EDGES
}

// ---------- binning pass: edges -> 196 dst-buckets, dense chunked writes ----------
__global__ void __launch_bounds__(256) k_bin(const int* __restrict__ ei,
                                             int* __restrict__ bcur,
                                             unsigned* __restrict__ binned) {
    __shared__ int bh[SCAN_BLOCKS];   // count, then local cursor
    __shared__ int bb[SCAN_BLOCKS];   // reserved global base
    int t = threadIdx.x;
    if (t < SCAN_BLOCKS) bh[t] = 0;
    __syncthreads();
    int e0 = blockIdx.x * BIN_CHUNK;
#pragma unroll 5
    for (int k = 0; k < BIN_CHUNK / 256; ++k) {
        int dst = ei[N_EDGES + e0 + t + k * 256];
        atomicAdd(&bh[dst >> 8], 1);
    }
    __syncthreads();
    if (t < SCAN_BLOCKS) {
        bb[t] = atomicAdd(&bcur[t], bh[t]);
        bh[t] = 0;
    }
    __syncthreads();
#pragma unroll 5
    for (int k = 0; k < BIN_CHUNK / 256; ++k) {
        int e = e0 + t + k * 256;
        int src = ei[e];
        int dst = ei[N_EDGES + e];
        int b = dst >> 8;
        int lo = atomicAdd(&bh[b], 1);
        binned[bb[b] + lo] = (unsigned)src | ((unsigned)(dst & 255) << 16);   // src < 2^16
    }
}

// ---------- fused per-bucket: count dsts + scan + rowstart + self-loop + scatter ----------
__global__ void __launch_bounds__(256) k_scatter3(const unsigned* __restrict__ binned,
                                                  const int* __restrict__ bbase,
                                                  int* __restrict__ rowstart,
                                                  int* __restrict__ csr_src) {
    __shared__ int lcnt[256];
    __shared__ int lcur[256];
    __shared__ int s[256];
    int t = threadIdx.x, b = blockIdx.x;
    int e0 = bbase[b], e1 = bbase[b + 1];
    lcnt[t] = 0;
    __syncthreads();
    for (int i = e0 + t; i < e1; i += 256)
        atomicAdd(&lcnt[binned[i] >> 16], 1);
    __syncthreads();
    int v = lcnt[t];
    s[t] = v;
    __syncthreads();
#pragma unroll
    for (int off = 1; off < 256; off <<= 1) {
        int u = (t >= off) ? s[t - off] : 0;
        __syncthreads();
        s[t] += u;
        __syncthreads();
    }
    int d = b * 256 + t;
    int base_b = e0 + 256 * b;              // edges before bucket + self-loops before bucket
    if (d < N_NODES) {
        int rs = base_b + (s[t] - v) + t;   // + t self-loops within bucket
        rowstart[d] = rs;
        csr_src[rs] = d;                    // self-loop edge placed first
        lcur[t] = rs + 1;
    } else lcur[t] = 0;
    if (b == 0 && t == 0) rowstart[N_NODES] = N_EDGES + N_NODES;
    __syncthreads();
    for (int i = e0 + t; i < e1; i += 256) {
        unsigned u = binned[i];
        int pos = atomicAdd(&lcur[u >> 16], 1);
        csr_src[pos] = (int)(u & 0xFFFFu);
    }
}

// ---------- aggregation, two-phase, int8 messages, 2-deep gather pipeline ----------
// phase A (lane==edge): gather smeta, ex = exp(leaky(si+sj)), exs = ex*scale -> LDS.
// Gather groups 0/1 are pre-issued right after csr arrives (overlap with exp math).
// phase B: alternating A/B banks, refill group g+2/g+3 while consuming g/g+1.
// Groups zero-padded to 8 (padding lanes alias csr[i1-1]'s row -> ~free).
__global__ void __launch_bounds__(256) k_aggregate(const int* __restrict__ rowstart,
                                                   const int* __restrict__ csr_src,
                                                   const float* __restrict__ sic,
                                                   const float* __restrict__ smeta,
                                                   const unsigned* __restrict__ Wx8,
                                                   unsigned* __restrict__ expb) {
    __shared__ float exls[4][64 * 4];                 // per-wave: 64 edges x 4 heads
    int wv = threadIdx.x >> 6;
    int dst = blockIdx.x * 4 + wv;                    // grid = 12500, exact
    int lane = threadIdx.x & 63;
    int kh = lane >> 4;
    int i0 = rowstart[dst], i1 = rowstart[dst + 1];
    float4 si = *(const float4*)&sic[(size_t)dst * 4];   // broadcast (ab folded)
    float* exl = exls[wv];
    const float* exb = exl + kh;
    const float4* sm4 = (const float4*)smeta;
    const char* wxp = (const char*)Wx8;
    size_t loff = (size_t)lane * 4;

    f2 acc01 = {0.f, 0.f}, acc23 = {0.f, 0.f};
    float den0 = 0.f, den1 = 0.f, den2 = 0.f, den3 = 0.f;
    float ds0 = 0.f, ds1 = 0.f, ds2 = 0.f, ds3 = 0.f;

    for (int b = i0; b < i1; b += 64) {
        int cnt = i1 - b;
        if (cnt > 64) cnt = 64;
        int ngrp = (cnt + 7) >> 3;
        // ---- phase A: one edge per lane ----
        int idx = b + lane;
        if (lane >= cnt) idx = i1 - 1;
        int sl = __builtin_nontemporal_load(&csr_src[idx]);
        float4 mj = sm4[(size_t)sl * 2];
        float4 ms = sm4[(size_t)sl * 2 + 1];
        // pre-issue gather groups 0 and 1 (depend only on sl)
        unsigned gA[8], gB[8];
#pragma unroll
        for (int u = 0; u < 8; ++u) {
            int s = __builtin_amdgcn_readlane(sl, u);
            gA[u] = *(const unsigned*)(wxp + (((size_t)(unsigned)s) << 8) + loff);
        }
        if (ngrp > 1) {
#pragma unroll
            for (int u = 0; u < 8; ++u) {
                int s = __builtin_amdgcn_readlane(sl, 8 + u);
                gB[u] = *(const unsigned*)(wxp + (((size_t)(unsigned)s) << 8) + loff);
            }
        }
        float xs0 = 0.f, xs1 = 0.f, xs2 = 0.f, xs3 = 0.f;
        if (lane < cnt) {
            float e0 = si.x + mj.x, e1 = si.y + mj.y;
            float e2 = si.z + mj.z, e3 = si.w + mj.w;
            e0 = fmaxf(e0, NEG_SLOPE * e0);
            e1 = fmaxf(e1, NEG_SLOPE * e1);
            e2 = fmaxf(e2, NEG_SLOPE * e2);
            e3 = fmaxf(e3, NEG_SLOPE * e3);
            float ex0 = __expf(e0), ex1 = __expf(e1);
            float ex2 = __expf(e2), ex3 = __expf(e3);
            den0 += ex0; den1 += ex1; den2 += ex2; den3 += ex3;
            xs0 = ex0 * ms.x; xs1 = ex1 * ms.y;
            xs2 = ex2 * ms.z; xs3 = ex3 * ms.w;
            ds0 += xs0; ds1 += xs1; ds2 += xs2; ds3 += xs3;
        }
        *(float4*)&exl[lane * 4] = make_float4(xs0, xs1, xs2, xs3);
        asm volatile("" ::: "memory");    // keep phase A stores before phase B reads
        // ---- phase B: consume groups, 2-bank pipeline ----
        for (int g = 0; g < ngrp; g += 2) {
#pragma unroll
            for (int u = 0; u < 8; ++u) {
                float ev = exb[(size_t)(g * 8 + u) * 4];
                f2 w01 = {(float)(gA[u] & 0xFFu), (float)((gA[u] >> 8) & 0xFFu)};
                f2 w23 = {(float)((gA[u] >> 16) & 0xFFu), (float)(gA[u] >> 24)};
                f2 e2 = {ev, ev};
                acc01 = __builtin_elementwise_fma(w01, e2, acc01);
                acc23 = __builtin_elementwise_fma(w23, e2, acc23);
            }
            if (g + 2 < ngrp) {
#pragma unroll
                for (int u = 0; u < 8; ++u) {
                    int s = __builtin_amdgcn_readlane(sl, (g + 2) * 8 + u);
                    gA[u] = *(const unsigned*)(wxp + (((size_t)(unsigned)s) << 8) + loff);
                }
            }
            if (g + 1 < ngrp) {
#pragma unroll
                for (int u = 0; u < 8; ++u) {
                    float ev = exb[(size_t)((g + 1) * 8 + u) * 4];
                    f2 w01 = {(float)(gB[u] & 0xFFu), (float)((gB[u] >> 8) & 0xFFu)};
                    f2 w23 = {(float)((gB[u] >> 16) & 0xFFu), (float)(gB[u] >> 24)};
                    f2 e2 = {ev, ev};
                    acc01 = __builtin_elementwise_fma(w01, e2, acc01);
                    acc23 = __builtin_elementwise_fma(w23, e2, acc23);
                }
                if (g + 3 < ngrp) {
#pragma unroll
                    for (int u = 0; u < 8; ++u) {
                        int s = __builtin_amdgcn_readlane(sl, (g + 3) * 8 + u);
                        gB[u] = *(const unsigned*)(wxp + (((size_t)(unsigned)s) << 8) + loff);
                    }
                }
            }
        }
        asm volatile("" ::: "memory");    // keep next batch's stores after these reads
    }

    // ---- den/dsum reduce: fold 16-lane groups, select my head, butterfly ----
    den0 += __shfl_xor(den0, 16, 64); den0 += __shfl_xor(den0, 32, 64);
    den1 += __shfl_xor(den1, 16, 64); den1 += __shfl_xor(den1, 32, 64);
    den2 += __shfl_xor(den2, 16, 64); den2 += __shfl_xor(den2, 32, 64);
    den3 += __shfl_xor(den3, 16, 64); den3 += __shfl_xor(den3, 32, 64);
    ds0 += __shfl_xor(ds0, 16, 64); ds0 += __shfl_xor(ds0, 32, 64);
    ds1 += __shfl_xor(ds1, 16, 64); ds1 += __shfl_xor(ds1, 32, 64);
    ds2 += __shfl_xor(ds2, 16, 64); ds2 += __shfl_xor(ds2, 32, 64);
    ds3 += __shfl_xor(ds3, 16, 64); ds3 += __shfl_xor(ds3, 32, 64);
    float dsel  = (kh < 2) ? ((kh == 0) ? den0 : den1) : ((kh == 2) ? den2 : den3);
    float dssel = (kh < 2) ? ((kh == 0) ? ds0  : ds1)  : ((kh == 2) ? ds2  : ds3);
#pragma unroll
    for (int off = 1; off <= 8; off <<= 1) {
        dsel  += __shfl_xor(dsel, off, 64);
        dssel += __shfl_xor(dssel, off, 64);
    }

    float r = 1.f / dsel;
    float bias = 128.f * dssel;
    float o0 = __expf((acc01.x - bias) * r), o1 = __expf((acc01.y - bias) * r);
    float o2 = __expf((acc23.x - bias) * r), o3 = __expf((acc23.y - bias) * r);
    unsigned long long pk = (unsigned long long)pack_bf16(o0, o1) |
                            ((unsigned long long)pack_bf16(o2, o3) << 32);
    __builtin_nontemporal_store(pk,
        (unsigned long long*)&expb[(size_t)dst * 128 + lane * 2]);  // bf16, cols 4l..4l+3
}

// ---------- column sums of exp(agg), bf16 input, 2 cols/thread ----------
__global__ void __launch_bounds__(256) k_colsum(const unsigned* __restrict__ expb,
                                                float* __restrict__ colsum) {
    int tid = threadIdx.x;
    int cp = tid & 127;            // uint index within row (cols 2cp, 2cp+1)
    int ro = tid >> 7;             // row parity
    int base = blockIdx.x * 196;
    int r1 = min(base + 196, N_NODES);
    float s0 = 0.f, s1 = 0.f;
    for (int r = base + ro; r < r1; r += 2) {
        unsigned u = expb[(size_t)r * 128 + cp];
        s0 += __uint_as_float(u << 16);
        s1 += __uint_as_float(u & 0xFFFF0000u);
    }
    atomicAdd(&colsum[2 * cp], s0);
    atomicAdd(&colsum[2 * cp + 1], s1);
}

// ---------- Ws frags: Ws[c][j] = Wo_w[j][c]/colsum[c], bf16 hi+residual, MFMA order ----------
// frag layout (matches k_setup convention): idx i -> e=i&7, lane=(i>>3)&63,
// ct=(i>>9)&3, kt=(i>>11)&7; c = kt*32+(lane>>4)*8+e (K dim), j = ct*16+(lane&15).
__global__ void k_prepWs(const float* __restrict__ Wo_w, const float* __restrict__ colsum,
                         ushort_t* __restrict__ Wsh, ushort_t* __restrict__ Wsl) {
    int i = blockIdx.x * 256 + threadIdx.x;   // 16384 total
    int e = i & 7, lane = (i >> 3) & 63, ct = (i >> 9) & 3, kt = (i >> 11) & 7;
    int c = kt * 32 + ((lane >> 4) << 3) + e;
    int j = ct * 16 + (lane & 15);
    float v = Wo_w[j * NC + c] / colsum[c];
    unsigned uv = __float_as_uint(v);
    unsigned vh = (uv + 0x7FFFu + ((uv >> 16) & 1u)) >> 16;
    float rem = v - __uint_as_float(vh << 16);
    unsigned ur = __float_as_uint(rem);
    unsigned vl = (ur + 0x7FFFu + ((ur >> 16) & 1u)) >> 16;
    Wsh[i] = (ushort_t)vh;
    Wsl[i] = (ushort_t)vl;
}

// ---------- out = expb @ (Wsh+Wsl) + b via MFMA; A = expb bf16 (exact) ----------
// Block = 16 nodes; wave wv owns col-tile wv (16 cols). 2 MFMA per kt (hi+lo).
__global__ void __launch_bounds__(256) k_out(const unsigned* __restrict__ expb,
                                             const uint4* __restrict__ Wsh,
                                             const uint4* __restrict__ Wsl,
                                             const float* __restrict__ Wo_b,
                                             float* __restrict__ out) {
    int n0 = blockIdx.x * 16;                  // 3125 exact
    int wv = __builtin_amdgcn_readfirstlane(threadIdx.x >> 6);
    int lane = threadIdx.x & 63;
    int arow = lane & 15, agrp = lane >> 4;
    const unsigned* ar = expb + (size_t)(n0 + arow) * 128 + agrp * 4;
    f4v acc = {0.f, 0.f, 0.f, 0.f};
#pragma unroll
    for (int kt = 0; kt < 8; ++kt) {
        uint4 av = *(const uint4*)(ar + kt * 16);       // 8 bf16: cols kt*32+agrp*8 ..+7
        uint4 bh = Wsh[(kt * 4 + wv) * 64 + lane];
        uint4 bl = Wsl[(kt * 4 + wv) * 64 + lane];
        s8v a8 = __builtin_bit_cast(s8v, av);
        acc = __builtin_amdgcn_mfma_f32_16x16x32_bf16(a8, __builtin_bit_cast(s8v, bh), acc, 0, 0, 0);
        acc = __builtin_amdgcn_mfma_f32_16x16x32_bf16(a8, __builtin_bit_cast(s8v, bl), acc, 0, 0, 0);
    }
    int j = wv * 16 + arow;                    // D: col = lane&15
    float bj = Wo_b[j];
#pragma unroll
    for (int r = 0; r < 4; ++r) {              // D: row = agrp*4 + r
        int node = n0 + agrp * 4 + r;
        out[(size_t)node * DH + j] = acc[r] + bj;
    }
}

extern "C" void kernel_launch(void* const* d_in, const int* in_sizes, int n_in,
                              void* d_out, int out_size, void* d_ws, size_t ws_size,
                              hipStream_t stream) {
    const int*   ei   = (const int*)d_in[0];     // int32 from harness
    const float* x    = (const float*)d_in[1];
    const float* Ww   = (const float*)d_in[2];
    const float* Wb   = (const float*)d_in[3];
    const float* aw   = (const float*)d_in[4];
    const float* ab   = (const float*)d_in[5];
    const float* Wo_w = (const float*)d_in[6];
    const float* Wo_b = (const float*)d_in[7];
    float* out = (float*)d_out;

    char* p = (char*)d_ws;
    auto alloc = [&](size_t bytes) -> char* {
        char* q = p;
        p += (bytes + 255) & ~(size_t)255;
        return q;
    };
    unsigned* Wx8      = (unsigned*)alloc((size_t)N_NODES * NC);    // int8 Wx copy (12.8MB)
    unsigned* expb     = (unsigned*)alloc((size_t)N_NODES * NC * 2);// bf16 exp(agg)
    ushort_t* Bh       = (ushort_t*)alloc((size_t)DX * NC * 2);     // bf16 W frags (hi)
    ushort_t* Bl       = (ushort_t*)alloc((size_t)DX * NC * 2);     // bf16 W frags (residual)
    ushort_t* Wsh      = (ushort_t*)alloc((size_t)NC * DH * 2);     // bf16 Ws frags (hi)
    ushort_t* Wsl      = (ushort_t*)alloc((size_t)NC * DH * 2);     // bf16 Ws frags (residual)
    float*    smeta    = (float*)alloc((size_t)N_NODES * 8 * 4);    // {sj[4], scale[4]} per node
    float*    sic      = (float*)alloc((size_t)N_NODES * 4 * 4);
    int*      rowstart = (int*)alloc((size_t)(N_NODES + 1) * 4);
    int*      csr_src  = (int*)alloc((size_t)(N_EDGES + N_NODES) * 4);
    unsigned* binned   = (unsigned*)alloc((size_t)N_EDGES * 4);
    float*    colsum   = (float*)alloc(NC * 4);
    int*      bcnt     = (int*)alloc(SCAN_BLOCKS * 4);
    int*      bbase    = (int*)alloc((SCAN_BLOCKS + 1) * 4);
    int*      bcur     = (int*)alloc(SCAN_BLOCKS * 4);

    k_setup<<<128, 256, 0, stream>>>(Ww, Bh, Bl, bcnt, colsum);
    k_gemm1<<<N_NODES / 16, 256, 0, stream>>>(x, (const uint4*)Bh, (const uint4*)Bl,
                                              Wb, aw, ab, Wx8, smeta, sic);
    k_bhist<<<BIN_BLOCKS, 256, 0, stream>>>(ei, bcnt);
    k_scanb<<<1, 256, 0, stream>>>(bcnt, bbase, bcur);
    k_bin<<<BIN_BLOCKS, 256, 0, stream>>>(ei, bcur, binned);
    k_scatter3<<<SCAN_BLOCKS, 256, 0, stream>>>(binned, bbase, rowstart, csr_src);
    k_aggregate<<<N_NODES / 4, 256, 0, stream>>>(rowstart, csr_src, sic, smeta, Wx8, expb);
    k_colsum<<<256, 256, 0, stream>>>(expb, colsum);
    k_prepWs<<<(NC * DH) / 256, 256, 0, stream>>>(Wo_w, colsum, Wsh, Wsl);
    k_out<<<N_NODES / 16, 256, 0, stream>>>(expb, (const uint4*)Wsh, (const uint4*)Wsl,
                                            Wo_b, out);
}